// Round 11
// baseline (3187.925 us; speedup 1.0000x reference)
//
#include <hip/hip_runtime.h>
#include <hip/hip_cooperative_groups.h>

namespace cg = cooperative_groups;

// ---- static problem config ----
#define B_ 4
#define Q_ 32
#define D_ 512
#define H_ 8
#define L_ 4
#define P_ 4
#define V_ 12000
#define T_ 16
#define HD_ 64
#define S_ 3840
#define BQ_ 128
#define NSTEP 15
#define NSLAB 94   // ceil(12000/128)
#define BSTR 520   // pinned-B LDS row stride (shorts)

typedef __attribute__((ext_vector_type(8))) short short8;
typedef __attribute__((ext_vector_type(4))) float f32x4;

__device__ inline unsigned short f2bf(float x) {
  union { float f; unsigned u; } v; v.f = x;
  unsigned u = v.u;
  unsigned r = (u + 0x7fffu + ((u >> 16) & 1u)) >> 16;  // RNE
  return (unsigned short)r;
}
__device__ inline float bf2f(unsigned short b) {
  union { unsigned u; float f; } v; v.u = ((unsigned)b) << 16; return v.f;
}
__device__ inline float fast_tanh(float x) {
  x = fminf(fmaxf(x, -15.f), 15.f);
  float e = __expf(2.f * x);
  return (e - 1.f) / (e + 1.f);
}
__device__ inline float sigmoidf_(float x) { return 1.f / (1.f + __expf(-x)); }

// ---------------- shared-memory structs ----------------
#define APAD 40
struct SmemGemm {            // double-buffered (fallback step kernels), ~42.5 KB
  unsigned short As0[128 * APAD], Bs0[128 * APAD];
  unsigned short As1[128 * APAD], Bs1[128 * APAD];
  float mred[128][2];
  float sred[128][2];
};
struct SmemGemmS {           // single-buffered (one-time kernels), ~20 KB
  unsigned short As[128 * APAD], Bs[128 * APAD];
};
struct SmemSample {
  float ctx_s[16][HD_];
  float aw_s[16];
  float wgt_s[16];
  float wred[4][16];
};
struct SmemOut {
  float ms[NSLAB];
  float ss[NSLAB];
  float lse;
};
union SmemSO { SmemSample s; SmemOut o; };

// ---------------- GEMM common pieces ----------------
__device__ inline short8 cvt8(float4 v0, float4 v1) {
  short8 p;
  p[0] = (short)f2bf(v0.x); p[1] = (short)f2bf(v0.y);
  p[2] = (short)f2bf(v0.z); p[3] = (short)f2bf(v0.w);
  p[4] = (short)f2bf(v1.x); p[5] = (short)f2bf(v1.y);
  p[6] = (short)f2bf(v1.z); p[7] = (short)f2bf(v1.w);
  return p;
}

__device__ inline void mfma_step(const unsigned short* As, const unsigned short* Bs,
                                 f32x4 acc[4][4], int wm, int wn, int lane) {
  int r15 = lane & 15, koct = (lane >> 4) * 8;
  short8 a[4], b[4];
#pragma unroll
  for (int mf = 0; mf < 4; mf++)
    a[mf] = *(const short8*)(As + (wm * 64 + mf * 16 + r15) * APAD + koct);
#pragma unroll
  for (int nf = 0; nf < 4; nf++)
    b[nf] = *(const short8*)(Bs + (wn * 64 + nf * 16 + r15) * APAD + koct);
#pragma unroll
  for (int mf = 0; mf < 4; mf++)
#pragma unroll
    for (int nf = 0; nf < 4; nf++)
      acc[mf][nf] = __builtin_amdgcn_mfma_f32_16x16x32_bf16(a[mf], b[nf], acc[mf][nf], 0, 0, 0);
}

// Pipelined K-loop: double-buffered LDS, ONE sync/iter, register prefetch.
template <int NT, class FA, class FB>
__device__ inline void gemm_pipe(FA loadA, FB loadB, SmemGemm& sm,
                                 f32x4 acc[4][4], int wm, int wn, int lane, int tid) {
  int r = tid >> 2, ko = (tid & 3) * 8;
  short8 a0, a1, b0, b1;
  loadA(0, a0, a1); loadB(0, b0, b1);
#pragma unroll
  for (int t = 0; t < NT; t++) {
    unsigned short* As = (t & 1) ? sm.As1 : sm.As0;
    unsigned short* Bs = (t & 1) ? sm.Bs1 : sm.Bs0;
    *(short8*)(As + r * APAD + ko) = a0;
    *(short8*)(As + (r + 64) * APAD + ko) = a1;
    *(short8*)(Bs + r * APAD + ko) = b0;
    *(short8*)(Bs + (r + 64) * APAD + ko) = b1;
    short8 na0, na1, nb0, nb1;
    if (t + 1 < NT) { loadA(t + 1, na0, na1); loadB(t + 1, nb0, nb1); }
    __syncthreads();
    mfma_step(As, Bs, acc, wm, wn, lane);
    if (t + 1 < NT) { a0 = na0; a1 = na1; b0 = nb0; b1 = nb1; }
  }
}

// Single-buffered loop (one-time kernels)
template <int NT, class FA, class FB>
__device__ inline void gemm_simple(FA loadA, FB loadB, SmemGemmS& sm,
                                   f32x4 acc[4][4], int wm, int wn, int lane, int tid) {
  int r = tid >> 2, ko = (tid & 3) * 8;
#pragma unroll 2
  for (int t = 0; t < NT; t++) {
    short8 a0, a1, b0, b1;
    loadA(t, a0, a1); loadB(t, b0, b1);
    *(short8*)(sm.As + r * APAD + ko) = a0;
    *(short8*)(sm.As + (r + 64) * APAD + ko) = a1;
    *(short8*)(sm.Bs + r * APAD + ko) = b0;
    *(short8*)(sm.Bs + (r + 64) * APAD + ko) = b1;
    __syncthreads();
    mfma_step(sm.As, sm.Bs, acc, wm, wn, lane);
    __syncthreads();
  }
}

// Pinned-B K-loop: B lives in LDS (BSTR stride); A double-buffered, 1 sync/iter.
template <int NT>
__device__ inline void gemm_pinB(const unsigned short* __restrict__ Asrc,
                                 const unsigned short* Bpin,
                                 unsigned short* Ab0, unsigned short* Ab1,
                                 f32x4 acc[4][4], int wm, int wn, int lane, int tid) {
  int r = tid >> 2, ko = (tid & 3) * 8;
  int r15 = lane & 15, koct = (lane >> 4) * 8;
  short8 a0 = *(const short8*)(Asrc + (size_t)r * 512 + ko);
  short8 a1 = *(const short8*)(Asrc + (size_t)(r + 64) * 512 + ko);
#pragma unroll
  for (int t = 0; t < NT; t++) {
    unsigned short* Ab = (t & 1) ? Ab1 : Ab0;
    *(short8*)(Ab + r * APAD + ko) = a0;
    *(short8*)(Ab + (r + 64) * APAD + ko) = a1;
    short8 na0, na1;
    if (t + 1 < NT) {
      na0 = *(const short8*)(Asrc + (size_t)r * 512 + (t + 1) * 32 + ko);
      na1 = *(const short8*)(Asrc + (size_t)(r + 64) * 512 + (t + 1) * 32 + ko);
    }
    __syncthreads();
    short8 af[4], bf[4];
#pragma unroll
    for (int mf = 0; mf < 4; mf++)
      af[mf] = *(const short8*)(Ab + (wm * 64 + mf * 16 + r15) * APAD + koct);
#pragma unroll
    for (int nf = 0; nf < 4; nf++)
      bf[nf] = *(const short8*)(Bpin + (size_t)(wn * 64 + nf * 16 + r15) * BSTR + t * 32 + koct);
#pragma unroll
    for (int mf = 0; mf < 4; mf++)
#pragma unroll
      for (int nf = 0; nf < 4; nf++)
        acc[mf][nf] = __builtin_amdgcn_mfma_f32_16x16x32_bf16(af[mf], bf[nf], acc[mf][nf], 0, 0, 0);
    if (t + 1 < NT) { a0 = na0; a1 = na1; }
  }
}

// D layout (HW-verified m89): col = lane&15, row = (lane>>4)*4 + j
__device__ inline void mfma_epilogue(float* __restrict__ out, int ldo, int m0, int n0,
                                     int Nmax, const float* __restrict__ bias,
                                     const unsigned char* __restrict__ mask,
                                     const float* __restrict__ base,
                                     f32x4 acc[4][4], int wm, int wn, int lane) {
  int rb = (lane >> 4) * 4, cb = lane & 15;
#pragma unroll
  for (int nf = 0; nf < 4; nf++) {
    int col = n0 + wn * 64 + nf * 16 + cb;
    if (col >= Nmax) continue;
    float bv = bias ? bias[col] : 0.f;
#pragma unroll
    for (int mf = 0; mf < 4; mf++) {
#pragma unroll
      for (int j = 0; j < 4; j++) {
        int row = m0 + wm * 64 + mf * 16 + rb + j;
        float v = acc[mf][nf][j] + bv;
        if (base) v += base[(size_t)row * ldo + col];
        if (mask && mask[row]) v = 0.f;
        out[(size_t)row * ldo + col] = v;
      }
    }
  }
}

__device__ inline void mfma_epilogue_bf16(unsigned short* __restrict__ out, int ldo, int n0,
                                          f32x4 acc[4][4], int wm, int wn, int lane) {
  int rb = (lane >> 4) * 4, cb = lane & 15;
#pragma unroll
  for (int nf = 0; nf < 4; nf++) {
    int col = n0 + wn * 64 + nf * 16 + cb;
#pragma unroll
    for (int mf = 0; mf < 4; mf++) {
#pragma unroll
      for (int j = 0; j < 4; j++) {
        int row = wm * 64 + mf * 16 + rb + j;
        out[(size_t)row * ldo + col] = f2bf(acc[mf][nf][j]);
      }
    }
  }
}

#define ACC_INIT f32x4 acc[4][4]; { f32x4 z = {0.f,0.f,0.f,0.f}; \
  _Pragma("unroll") for (int i_=0;i_<4;i_++) _Pragma("unroll") for (int j_=0;j_<4;j_++) acc[i_][j_]=z; }

// ================= shared device role functions =================

__device__ void do_pre(const unsigned short* __restrict__ hbf,
    const unsigned short* __restrict__ offWbf, const unsigned short* __restrict__ awWbf,
    const unsigned short* __restrict__ hsWbf, const float* __restrict__ hsb,
    const float* __restrict__ off_base, const float* __restrict__ aw_base,
    float* __restrict__ offo, float* __restrict__ awo, float* __restrict__ hpo,
    SmemGemm& sm, int blk) {
  const unsigned short* Bw; const float* bias; const float* base;
  float* out; int ldkB, n0, ldo;
  if (blk == 0)      { Bw = offWbf; bias = nullptr; base = off_base; out = offo; ldkB = 1024; n0 = 0; ldo = 128; }
  else if (blk == 1) { Bw = awWbf;  bias = nullptr; base = aw_base;  out = awo;  ldkB = 1024; n0 = 0; ldo = 128; }
  else { Bw = hsWbf; bias = hsb; base = nullptr; out = hpo; ldkB = 512; n0 = (blk - 2) * 128; ldo = 512; }
  int tid = threadIdx.x;
  int lane = tid & 63, w = tid >> 6, wm = w >> 1, wn = w & 1;
  int r = tid >> 2, ko = (tid & 3) * 8;
  ACC_INIT;
  gemm_pipe<16>(
    [&](int t, short8& x, short8& y) {
      x = *(const short8*)(hbf + (size_t)r * 512 + t * 32 + ko);
      y = *(const short8*)(hbf + (size_t)(r + 64) * 512 + t * 32 + ko);
    },
    [&](int t, short8& x, short8& y) {
      x = *(const short8*)(Bw + (size_t)(n0 + r) * ldkB + t * 32 + ko);
      y = *(const short8*)(Bw + (size_t)(n0 + r + 64) * ldkB + t * 32 + ko);
    },
    sm, acc, wm, wn, lane, tid);
  mfma_epilogue(out, ldo, 0, n0, ldo, bias, nullptr, base, acc, wm, wn, lane);
}

__device__ void do_logits_lse(const unsigned short* __restrict__ hbf,
    const unsigned short* __restrict__ Wbf, const float* __restrict__ bias,
    float* __restrict__ logits, float* __restrict__ m_sb, float* __restrict__ s_sb,
    SmemGemm& sm, int slab) {
  int tid = threadIdx.x;
  int lane = tid & 63, w = tid >> 6, wm = w >> 1, wn = w & 1;
  int r = tid >> 2, ko = (tid & 3) * 8;
  int n0 = slab * 128;
  bool ok0 = (n0 + r) < V_, ok1 = (n0 + r + 64) < V_;
  ACC_INIT;
  gemm_pipe<16>(
    [&](int t, short8& x, short8& y) {
      x = *(const short8*)(hbf + (size_t)r * 512 + t * 32 + ko);
      y = *(const short8*)(hbf + (size_t)(r + 64) * 512 + t * 32 + ko);
    },
    [&](int t, short8& x, short8& y) {
      short8 z = {0, 0, 0, 0, 0, 0, 0, 0};
      x = ok0 ? *(const short8*)(Wbf + (size_t)(n0 + r) * 512 + t * 32 + ko) : z;
      y = ok1 ? *(const short8*)(Wbf + (size_t)(n0 + r + 64) * 512 + t * 32 + ko) : z;
    },
    sm, acc, wm, wn, lane, tid);
  int rb = (lane >> 4) * 4, cb = lane & 15;
#pragma unroll
  for (int mf = 0; mf < 4; mf++) {
#pragma unroll
    for (int j = 0; j < 4; j++) {
      int row = wm * 64 + mf * 16 + rb + j;
      float vv[4];
      float mx = -3.4e38f;
#pragma unroll
      for (int nf = 0; nf < 4; nf++) {
        int col = n0 + wn * 64 + nf * 16 + cb;
        bool ok = col < V_;
        float v = ok ? (acc[mf][nf][j] + bias[col]) : -3.4e38f;
        if (ok) logits[(size_t)row * V_ + col] = v;
        vv[nf] = v;
        mx = fmaxf(mx, v);
      }
#pragma unroll
      for (int o = 8; o; o >>= 1) mx = fmaxf(mx, __shfl_xor(mx, o, 16));
      float sme = 0.f;
#pragma unroll
      for (int nf = 0; nf < 4; nf++) sme += (vv[nf] > -3.0e38f) ? __expf(vv[nf] - mx) : 0.f;
#pragma unroll
      for (int o = 8; o; o >>= 1) sme += __shfl_xor(sme, o, 16);
      if (cb == 0) { sm.mred[row][wn] = mx; sm.sred[row][wn] = sme; }
    }
  }
  __syncthreads();
  if (tid < 128) {
    float m0 = sm.mred[tid][0], m1 = sm.mred[tid][1];
    float M = fmaxf(m0, m1);
    float Ssum = sm.sred[tid][0] * __expf(m0 - M) + sm.sred[tid][1] * __expf(m1 - M);
    m_sb[tid * 96 + slab] = M;
    s_sb[tid * 96 + slab] = Ssum;
  }
}

__device__ void do_out(const float* __restrict__ logits, const float* __restrict__ m_sb,
                       const float* __restrict__ s_sb, float* __restrict__ outp, int t,
                       int row, SmemOut& sm) {
  int tid = threadIdx.x;
  if (tid < NSLAB) { sm.ms[tid] = m_sb[row * 96 + tid]; sm.ss[tid] = s_sb[row * 96 + tid]; }
  __syncthreads();
  if (tid < 64) {
    float m = -3.4e38f, s = 0.f;
    for (int i = tid; i < NSLAB; i += 64) {
      float mi = sm.ms[i], si = sm.ss[i];
      float M = fmaxf(m, mi);
      s = s * __expf(m - M) + si * __expf(mi - M);
      m = M;
    }
#pragma unroll
    for (int o = 32; o; o >>= 1) {
      float mo = __shfl_xor(m, o, 64), so = __shfl_xor(s, o, 64);
      float M = fmaxf(m, mo);
      s = s * __expf(m - M) + so * __expf(mo - M);
      m = M;
    }
    if (tid == 0) sm.lse = m + __logf(s);
  }
  __syncthreads();
  float lse = sm.lse;
  const float4* lp = (const float4*)(logits + (size_t)row * V_);
  float4* op = (float4*)(outp + ((size_t)row * (T_ - 1) + t) * V_);
  for (int i = tid; i < V_ / 4; i += 256) {
    float4 v = lp[i];
    v.x -= lse; v.y -= lse; v.z -= lse; v.w -= lse;
    op[i] = v;
  }
  __syncthreads();
}

__device__ void do_sample(const float* __restrict__ value, const float* __restrict__ offo,
    const float* __restrict__ awo, const float* __restrict__ hp_base, int hstride,
    const float* __restrict__ refp, const float* __restrict__ vrat,
    const float* __restrict__ ctxWT, const float* __restrict__ ctxb,
    const float* __restrict__ alphaW, const float* __restrict__ alphab,
    unsigned short* __restrict__ attnbf, int blk, SmemSample& sm) {
  int bq = blk >> 3, h = blk & 7;
  int b = bq >> 5;
  int tid = threadIdx.x;
  int lane = tid & 63, wid = tid >> 6;

  if (tid < 16) {
    float v = awo[bq * 128 + h * 16 + tid];
    float m = v;
#pragma unroll
    for (int o = 8; o; o >>= 1) m = fmaxf(m, __shfl_xor(m, o, 16));
    float e = __expf(v - m);
    float s = e;
#pragma unroll
    for (int o = 8; o; o >>= 1) s += __shfl_xor(s, o, 16);
    sm.aw_s[tid] = e / s;
  }
  __syncthreads();

  {
    const int TSv[4] = {2048, 1024, 512, 256};
    const int LSv[4] = {0, 2048, 3072, 3584};
    float ref = refp[bq];
    int hd = tid & 63;
#pragma unroll
    for (int pp = 0; pp < 4; pp++) {
      int p = pp * 4 + (tid >> 6);
      int l = p >> 2;
      int Tl = TSv[l];
      float off = offo[bq * 128 + h * 16 + p];
      float loc = ref * vrat[b * L_ + l] + off / (float)Tl;
      float x = loc * (float)Tl - 0.5f;
      float x0 = floorf(x);
      float wf = x - x0;
      int i0 = (int)x0;
      const float* vb = value + ((size_t)(b * S_ + LSv[l]) * D_) + h * HD_ + hd;
      float v0 = (i0 >= 0 && i0 < Tl) ? vb[(size_t)i0 * D_] : 0.f;
      float v1 = (i0 + 1 >= 0 && i0 + 1 < Tl) ? vb[(size_t)(i0 + 1) * D_] : 0.f;
      sm.ctx_s[p][hd] = (v0 * (1.f - wf) + v1 * wf) * sm.aw_s[p];
    }
  }
  __syncthreads();

  float2 sacc[16];
#pragma unroll
  for (int p = 0; p < 16; p++) { sacc[p].x = 0.f; sacc[p].y = 0.f; }
  for (int k4 = 0; k4 < 16; k4++) {
    float2 wv[4];
#pragma unroll
    for (int kk = 0; kk < 4; kk++)
      wv[kk] = *(const float2*)(ctxWT + (k4 * 4 + kk) * 512 + 2 * tid);
#pragma unroll
    for (int p = 0; p < 16; p++) {
      float4 c = *(const float4*)(&sm.ctx_s[p][k4 * 4]);
      sacc[p].x += c.x * wv[0].x + c.y * wv[1].x + c.z * wv[2].x + c.w * wv[3].x;
      sacc[p].y += c.x * wv[0].y + c.y * wv[1].y + c.z * wv[2].y + c.w * wv[3].y;
    }
  }

  {
    float2 cb = *(const float2*)(ctxb + 2 * tid);
    float2 hp = *(const float2*)(hp_base + (size_t)hstride * bq + 2 * tid);
    float2 al = *(const float2*)(alphaW + 2 * tid);
    float part[16];
#pragma unroll
    for (int p = 0; p < 16; p++)
      part[p] = al.x * fast_tanh(sacc[p].x + cb.x + hp.x) +
                al.y * fast_tanh(sacc[p].y + cb.y + hp.y);
#pragma unroll
    for (int o = 32; o; o >>= 1)
#pragma unroll
      for (int p = 0; p < 16; p++) part[p] += __shfl_xor(part[p], o, 64);
    if (lane == 0)
#pragma unroll
      for (int p = 0; p < 16; p++) sm.wred[wid][p] = part[p];
  }
  __syncthreads();
  if (tid < 16) {
    float v = sm.wred[0][tid] + sm.wred[1][tid] + sm.wred[2][tid] + sm.wred[3][tid] + alphab[0];
    float m = v;
#pragma unroll
    for (int o = 8; o; o >>= 1) m = fmaxf(m, __shfl_xor(m, o, 16));
    float e = __expf(v - m);
    float s = e;
#pragma unroll
    for (int o = 8; o; o >>= 1) s += __shfl_xor(s, o, 16);
    sm.wgt_s[tid] = e / s;
  }
  __syncthreads();
  if (tid < 64) {
    float a = 0.f;
#pragma unroll
    for (int pi = 0; pi < 16; pi++) a += sm.wgt_s[pi] * sm.ctx_s[pi][tid];
    attnbf[bq * D_ + h * HD_ + tid] = f2bf(a);
  }
  __syncthreads();
}

// ================= one-time kernels =================

__global__ __launch_bounds__(256) void k_prep(const float* __restrict__ logitW,
    const float* __restrict__ Wih, const float* __restrict__ Whh,
    const float* __restrict__ offW, const float* __restrict__ awW,
    const float* __restrict__ hsW, const float* __restrict__ valueW,
    const float* __restrict__ query, const float* __restrict__ ctxW,
    const int* __restrict__ seq, const float* __restrict__ embedW,
    unsigned short* __restrict__ logitWbf, unsigned short* __restrict__ Wihbf,
    unsigned short* __restrict__ Whhbf, unsigned short* __restrict__ offWbf,
    unsigned short* __restrict__ awWbf, unsigned short* __restrict__ hsWbf,
    unsigned short* __restrict__ valueWbf, unsigned short* __restrict__ qbf,
    float* __restrict__ ctxWT, unsigned short* __restrict__ hbf0, float* __restrict__ c0,
    unsigned short* __restrict__ xembbf) {
  int gi = blockIdx.x * 256 + threadIdx.x;
  const int e0 = 1536000, e1 = e0 + 786432, e2 = e1 + 262144, e3 = e2 + 32768,
            e4 = e3 + 32768, e5 = e4 + 65536, e6 = e5 + 65536, e7 = e6 + 16384;
  const int e8 = e7 + 16384, e9 = e8 + 8192, e10 = e9 + 245760;
  if (gi < e7) {
    const float* src; unsigned short* dst; int lo, dsti;
    if (gi < e0)      { src = logitW; dst = logitWbf; lo = gi; dsti = lo; }
    else if (gi < e1) {
      src = Wih; dst = Wihbf; lo = gi - e0;
      int row = lo / 384, c4 = lo - row * 384;
      int g = row >> 9, d = row & 511, n = d >> 5, rr = d & 31;
      dsti = (n * 128 + g * 32 + rr) * 384 + c4;
    }
    else if (gi < e2) {
      src = Whh; dst = Whhbf; lo = gi - e1;
      int row = lo >> 7, c4 = lo & 127;
      int g = row >> 9, d = row & 511, n = d >> 5, rr = d & 31;
      dsti = (n * 128 + g * 32 + rr) * 128 + c4;
    }
    else if (gi < e3) { src = offW;   dst = offWbf;   lo = gi - e2; dsti = lo; }
    else if (gi < e4) { src = awW;    dst = awWbf;    lo = gi - e3; dsti = lo; }
    else if (gi < e5) { src = hsW;    dst = hsWbf;    lo = gi - e4; dsti = lo; }
    else if (gi < e6) { src = valueW; dst = valueWbf; lo = gi - e5; dsti = lo; }
    else              { src = query;  dst = qbf;      lo = gi - e6; dsti = lo; }
    float4 v = ((const float4*)src)[lo];
    ushort4 o;
    o.x = f2bf(v.x); o.y = f2bf(v.y); o.z = f2bf(v.z); o.w = f2bf(v.w);
    ((ushort4*)dst)[dsti] = o;
  } else if (gi < e8) {
    int i = gi - e7;
    ushort4 z4; z4.x = 0; z4.y = 0; z4.z = 0; z4.w = 0;
    ((ushort4*)hbf0)[i] = z4;
    float4 z = {0.f, 0.f, 0.f, 0.f};
    ((float4*)c0)[i] = z;
  } else if (gi < e9) {
    int i = gi - e8;
    int k = i >> 7, d4 = i & 127;
    float4 o;
    o.x = ctxW[(d4 * 4 + 0) * 64 + k];
    o.y = ctxW[(d4 * 4 + 1) * 64 + k];
    o.z = ctxW[(d4 * 4 + 2) * 64 + k];
    o.w = ctxW[(d4 * 4 + 3) * 64 + k];
    ((float4*)ctxWT)[k * 128 + d4] = o;
  } else if (gi < e10) {
    int i = gi - e9;
    int row = i >> 7, d4 = i & 127;
    int t = row >> 7, bq = row & 127;
    int tok = seq[bq * T_ + t];
    float4 v = ((const float4*)embedW)[(size_t)tok * 128 + d4];
    ushort4 o;
    o.x = f2bf(v.x); o.y = f2bf(v.y); o.z = f2bf(v.z); o.w = f2bf(v.w);
    ((ushort4*)xembbf)[(size_t)row * 128 + d4] = o;
  }
}

__global__ __launch_bounds__(256) void k_value(const float* __restrict__ enc,
    const unsigned short* __restrict__ valueWbf, const float* __restrict__ valueb,
    const unsigned char* __restrict__ mask, float* __restrict__ value) {
  __shared__ SmemGemmS sm;
  int blk = blockIdx.x;
  int xcd = blk & 7, j = blk >> 3;
  int m0 = (xcd * 15 + (j >> 2)) * 128, n0 = (j & 3) * 128;
  int tid = threadIdx.x;
  int lane = tid & 63, w = tid >> 6, wm = w >> 1, wn = w & 1;
  int r = tid >> 2, ko = (tid & 3) * 8;
  ACC_INIT;
  gemm_simple<16>(
    [&](int t, short8& x, short8& y) {
      const float4* s0 = (const float4*)(enc + (size_t)(m0 + r) * 512 + t * 32 + ko);
      const float4* s1 = (const float4*)(enc + (size_t)(m0 + r + 64) * 512 + t * 32 + ko);
      x = cvt8(s0[0], s0[1]); y = cvt8(s1[0], s1[1]);
    },
    [&](int t, short8& x, short8& y) {
      x = *(const short8*)(valueWbf + (size_t)(n0 + r) * 512 + t * 32 + ko);
      y = *(const short8*)(valueWbf + (size_t)(n0 + r + 64) * 512 + t * 32 + ko);
    },
    sm, acc, wm, wn, lane, tid);
  mfma_epilogue(value, 512, m0, n0, 512, valueb, mask, nullptr, acc, wm, wn, lane);
}

__global__ __launch_bounds__(256) void k_qg(const unsigned short* __restrict__ qbf,
    const unsigned short* __restrict__ offWbf, const float* __restrict__ offb,
    const unsigned short* __restrict__ awWbf, const float* __restrict__ awb,
    float* __restrict__ off_base, float* __restrict__ aw_base,
    const unsigned short* __restrict__ xembbf,
    const unsigned short* __restrict__ Wihbf, unsigned short* __restrict__ gates_base) {
  __shared__ SmemGemmS sm;
  int blk = blockIdx.x;
  int tid = threadIdx.x;
  int lane = tid & 63, w = tid >> 6, wm = w >> 1, wn = w & 1;
  int r = tid >> 2, ko = (tid & 3) * 8;
  if (blk < 2) {
    const unsigned short* Bw = blk ? awWbf : offWbf;
    const float* bias = blk ? awb : offb;
    float* out = blk ? aw_base : off_base;
    ACC_INIT;
    gemm_simple<16>(
      [&](int t, short8& x, short8& y) {
        x = *(const short8*)(qbf + (size_t)r * 512 + t * 32 + ko);
        y = *(const short8*)(qbf + (size_t)(r + 64) * 512 + t * 32 + ko);
      },
      [&](int t, short8& x, short8& y) {
        x = *(const short8*)(Bw + (size_t)r * 1024 + 512 + t * 32 + ko);
        y = *(const short8*)(Bw + (size_t)(r + 64) * 1024 + 512 + t * 32 + ko);
      },
      sm, acc, wm, wn, lane, tid);
    mfma_epilogue(out, 128, 0, 0, 128, bias, nullptr, nullptr, acc, wm, wn, lane);
  } else {
    int g = blk - 2;
    int xcd = g & 7, j = g >> 3;
    int n0 = (xcd * 2 + (j >= 15)) * 128;
    int st = (j >= 15) ? (j - 15) : j;
    const unsigned short* xa = xembbf + (size_t)(st * 128) * 512;
    ACC_INIT;
    gemm_simple<32>(
      [&](int t, short8& x, short8& y) {
        const unsigned short* src = (t < 16) ? xa : qbf;
        int kk = (t < 16) ? t * 32 : (t - 16) * 32;
        x = *(const short8*)(src + (size_t)r * 512 + kk + ko);
        y = *(const short8*)(src + (size_t)(r + 64) * 512 + kk + ko);
      },
      [&](int t, short8& x, short8& y) {
        int kk = (t < 16) ? t * 32 : 1024 + (t - 16) * 32;
        x = *(const short8*)(Wihbf + (size_t)(n0 + r) * 1536 + kk + ko);
        y = *(const short8*)(Wihbf + (size_t)(n0 + r + 64) * 1536 + kk + ko);
      },
      sm, acc, wm, wn, lane, tid);
    mfma_epilogue_bf16(gates_base + (size_t)st * 128 * 2048, 2048, n0, acc, wm, wn, lane);
  }
}

__global__ __launch_bounds__(256) void k_sample0(const float* __restrict__ value,
    const float* __restrict__ off_base, const float* __restrict__ aw_base,
    const float* __restrict__ hsb, const float* __restrict__ refp,
    const float* __restrict__ vrat, const float* __restrict__ ctxWT,
    const float* __restrict__ ctxb, const float* __restrict__ alphaW,
    const float* __restrict__ alphab, unsigned short* __restrict__ attnbf) {
  __shared__ SmemSample sm;
  do_sample(value, off_base, aw_base, hsb, 0, refp, vrat, ctxWT, ctxb, alphaW, alphab,
            attnbf, blockIdx.x, sm);
}

// ================= fallback per-step kernels (R9, proven) =================

__global__ __launch_bounds__(256) void k_lstm_gemm(
    const unsigned short* __restrict__ attnbf, const unsigned short* __restrict__ hbf,
    const unsigned short* __restrict__ Wihbf, const unsigned short* __restrict__ Whhbf,
    float* __restrict__ gpart) {
  __shared__ SmemGemm sm;
  int tid = threadIdx.x;
  int lane = tid & 63, w = tid >> 6, wm = w >> 1, wn = w & 1;
  int r = tid >> 2, ko = (tid & 3) * 8;
  int n0 = blockIdx.x * 128;
  int kc = blockIdx.y;
  const unsigned short* Asrc = (kc < 2) ? (attnbf + kc * 256) : (hbf + (kc - 2) * 256);
  const unsigned short* Bsrc = (kc < 2) ? (Wihbf + (size_t)n0 * 1536 + 512 + kc * 256)
                                        : (Whhbf + (size_t)n0 * 512 + (kc - 2) * 256);
  int ldB = (kc < 2) ? 1536 : 512;
  ACC_INIT;
  gemm_pipe<8>(
    [&](int t, short8& x, short8& y) {
      x = *(const short8*)(Asrc + (size_t)r * 512 + t * 32 + ko);
      y = *(const short8*)(Asrc + (size_t)(r + 64) * 512 + t * 32 + ko);
    },
    [&](int t, short8& x, short8& y) {
      x = *(const short8*)(Bsrc + (size_t)r * ldB + t * 32 + ko);
      y = *(const short8*)(Bsrc + (size_t)(r + 64) * ldB + t * 32 + ko);
    },
    sm, acc, wm, wn, lane, tid);
  mfma_epilogue(gpart + (size_t)kc * 262144, 2048, 0, n0, 2048,
                nullptr, nullptr, nullptr, acc, wm, wn, lane);
}

__global__ __launch_bounds__(256) void k_cell(const float* __restrict__ gpart,
    const unsigned short* __restrict__ gbase_t,
    const float* __restrict__ c, float* __restrict__ cn, unsigned short* __restrict__ hbf) {
  int idx = blockIdx.x * 256 + threadIdx.x;
  int bq = idx >> 9, d = idx & 511;
  int n = d >> 5, rr = d & 31;
  size_t rowoff = (size_t)bq * 2048 + n * 128 + rr;
  float g4[4];
#pragma unroll
  for (int gate = 0; gate < 4; gate++) {
    size_t off = rowoff + gate * 32;
    float s = bf2f(gbase_t[off]);
    s += gpart[off] + gpart[262144 + off] + gpart[2 * 262144 + off] + gpart[3 * 262144 + off];
    g4[gate] = s;
  }
  float cc = c[idx];
  float c2 = sigmoidf_(g4[1]) * cc + sigmoidf_(g4[0]) * fast_tanh(g4[2]);
  float h2 = sigmoidf_(g4[3]) * fast_tanh(c2);
  cn[idx] = c2;
  hbf[idx] = f2bf(h2);
}

__global__ __launch_bounds__(256) void k_logits_pre(const unsigned short* __restrict__ hnew,
    const unsigned short* __restrict__ logitWbf, const float* __restrict__ logitb,
    float* __restrict__ logits, float* __restrict__ m_sb, float* __restrict__ s_sb,
    const unsigned short* __restrict__ offWbf, const unsigned short* __restrict__ awWbf,
    const unsigned short* __restrict__ hsWbf, const float* __restrict__ hsb,
    const float* __restrict__ off_base, const float* __restrict__ aw_base,
    float* __restrict__ offo, float* __restrict__ awo, float* __restrict__ hpo) {
  __shared__ SmemGemm sm;
  int blk = blockIdx.x;
  if (blk < NSLAB)
    do_logits_lse(hnew, logitWbf, logitb, logits, m_sb, s_sb, sm, blk);
  else
    do_pre(hnew, offWbf, awWbf, hsWbf, hsb, off_base, aw_base, offo, awo, hpo,
           sm, blk - NSLAB);
}

__global__ __launch_bounds__(256) void k_out_sample(const float* __restrict__ logits,
    const float* __restrict__ m_sb, const float* __restrict__ s_sb,
    float* __restrict__ outp, int t,
    const float* __restrict__ value, const float* __restrict__ offo,
    const float* __restrict__ awo, const float* __restrict__ hproj,
    const float* __restrict__ refp, const float* __restrict__ vrat,
    const float* __restrict__ ctxWT, const float* __restrict__ ctxb,
    const float* __restrict__ alphaW, const float* __restrict__ alphab,
    unsigned short* __restrict__ attnbf) {
  __shared__ SmemSO sm;
  int blk = blockIdx.x;
  if (blk < 128)
    do_out(logits, m_sb, s_sb, outp, t, blk, sm.o);
  else
    do_sample(value, offo, awo, hproj, 512, refp, vrat, ctxWT, ctxb, alphaW, alphab,
              attnbf, blk - 128, sm.s);
}

// ================= persistent cooperative step-loop kernel (STATIC LDS) =========

struct PArgs {
  const float *value, *refp, *vrat, *ctxWT, *ctxb, *alphaW, *alphab;
  const float *logitb, *hsb, *off_base, *aw_base;
  float *offo, *awo, *hproj, *logits, *m_sb, *s_sb, *gpart, *c0, *c1, *outp;
  const unsigned short *logitWbf, *Wihbf, *Whhbf, *offWbf, *awWbf, *hsWbf, *gates_base;
  unsigned short *hbf0, *hbf1, *attnbf;
};

__global__ void __launch_bounds__(256, 1) k_persist(PArgs p) {
  // static LDS: 133120 + 20480 + 2048 = 155648 B (< 160 KiB per-WG on gfx950)
  __shared__ unsigned short Bpin[128 * BSTR];   // 133120 B
  __shared__ char scratch[20480];               // A dbuf OR sample/out scratch
  __shared__ float mred[128][2], sred[128][2];  // 2048 B
  unsigned short* Ab0 = (unsigned short*)scratch;
  unsigned short* Ab1 = (unsigned short*)(scratch + 10240);
  SmemSample& smp = *(SmemSample*)scratch;
  SmemOut&    smo = *(SmemOut*)scratch;

  cg::grid_group grid = cg::this_grid();
  int blk = blockIdx.x, tid = threadIdx.x;
  int lane = tid & 63, w = tid >> 6, wm = w >> 1, wn = w & 1;
  int r = tid >> 2, kb = (tid & 3) * 8;

  // ---- pin phase (per-block local, no grid sync needed) ----
  if (blk < NSLAB) {
    int n0 = blk * 128;
#pragma unroll
    for (int half = 0; half < 2; half++) {
      int row = r + half * 64;
      bool ok = (n0 + row) < V_;
      for (int kk = kb; kk < 512; kk += 32) {
        short8 v = {0, 0, 0, 0, 0, 0, 0, 0};
        if (ok) v = *(const short8*)(p.logitWbf + (size_t)(n0 + row) * 512 + kk);
        *(short8*)(Bpin + (size_t)row * BSTR + kk) = v;
      }
    }
  } else if (blk < 158) {
    int g = blk - 94, n0 = (g & 15) * 128, kc = g >> 4;
    const unsigned short* src; int ldb;
    if (kc < 2) { src = p.Wihbf + 512 + kc * 256; ldb = 1536; }
    else        { src = p.Whhbf + (kc - 2) * 256; ldb = 512; }
#pragma unroll
    for (int half = 0; half < 2; half++) {
      int row = r + half * 64;
      for (int kk = kb; kk < 256; kk += 32)
        *(short8*)(Bpin + (size_t)row * BSTR + kk) =
            *(const short8*)(src + (size_t)(n0 + row) * ldb + kk);
    }
  } else if (blk < 164) {
    int pr = blk - 158;
    const unsigned short* src; int ldb; int rbase = 0;
    if (pr == 0)      { src = p.offWbf; ldb = 1024; }
    else if (pr == 1) { src = p.awWbf;  ldb = 1024; }
    else              { src = p.hsWbf;  ldb = 512; rbase = (pr - 2) * 128; }
#pragma unroll
    for (int half = 0; half < 2; half++) {
      int row = r + half * 64;
      for (int kk = kb; kk < 512; kk += 32)
        *(short8*)(Bpin + (size_t)row * BSTR + kk) =
            *(const short8*)(src + (size_t)(rbase + row) * ldb + kk);
    }
  }
  __syncthreads();

  int orow = (blk >= 164) ? (blk - 164) : (blk < 36 ? 92 + blk : -1);

  for (int t = 0; t < NSTEP; t++) {
    const unsigned short* hcur = (t & 1) ? p.hbf1 : p.hbf0;
    unsigned short* hnxt = (t & 1) ? p.hbf0 : p.hbf1;
    const float* ccur = (t & 1) ? p.c1 : p.c0;
    float* cnxt = (t & 1) ? p.c0 : p.c1;

    // ---- P1: lstm split-K gemm (blks 94..157)  ||  out(t-1) ----
    if (blk >= 94 && blk < 158) {
      int g = blk - 94, n0 = (g & 15) * 128, kc = g >> 4;
      const unsigned short* Asrc = (kc < 2) ? (p.attnbf + kc * 256) : (hcur + (kc - 2) * 256);
      ACC_INIT;
      gemm_pinB<8>(Asrc, Bpin, Ab0, Ab1, acc, wm, wn, lane, tid);
      mfma_epilogue(p.gpart + (size_t)kc * 262144, 2048, 0, n0, 2048,
                    nullptr, nullptr, nullptr, acc, wm, wn, lane);
    } else if (t > 0 && orow >= 0) {
      do_out(p.logits, p.m_sb, p.s_sb, p.outp, t - 1, orow, smo);
    }
    grid.sync();

    // ---- P2: cell (all blocks, 1 elem/thread) ----
    {
      const unsigned short* gbase = p.gates_base + (size_t)t * 262144;
      int idx = blk * 256 + tid;
      int bq = idx >> 9, d = idx & 511;
      int n = d >> 5, rr = d & 31;
      size_t rowoff = (size_t)bq * 2048 + n * 128 + rr;
      float g4[4];
#pragma unroll
      for (int gate = 0; gate < 4; gate++) {
        size_t off = rowoff + gate * 32;
        float s = bf2f(gbase[off]);
        s += p.gpart[off] + p.gpart[262144 + off] + p.gpart[2 * 262144 + off] +
             p.gpart[3 * 262144 + off];
        g4[gate] = s;
      }
      float cc = ccur[idx];
      float c2 = sigmoidf_(g4[1]) * cc + sigmoidf_(g4[0]) * fast_tanh(g4[2]);
      float h2 = sigmoidf_(g4[3]) * fast_tanh(c2);
      cnxt[idx] = c2;
      hnxt[idx] = f2bf(h2);
    }
    grid.sync();

    // ---- P3: logits slabs (blks 0..93) + pre (blks 158..163) ----
    if (blk < NSLAB) {
      int n0 = blk * 128;
      ACC_INIT;
      gemm_pinB<16>(hnxt, Bpin, Ab0, Ab1, acc, wm, wn, lane, tid);
      int rb = (lane >> 4) * 4, cb = lane & 15;
#pragma unroll
      for (int mf = 0; mf < 4; mf++) {
#pragma unroll
        for (int j = 0; j < 4; j++) {
          int row = wm * 64 + mf * 16 + rb + j;
          float vv[4];
          float mx = -3.4e38f;
#pragma unroll
          for (int nf = 0; nf < 4; nf++) {
            int col = n0 + wn * 64 + nf * 16 + cb;
            bool ok = col < V_;
            float v = ok ? (acc[mf][nf][j] + p.logitb[col]) : -3.4e38f;
            if (ok) p.logits[(size_t)row * V_ + col] = v;
            vv[nf] = v;
            mx = fmaxf(mx, v);
          }
#pragma unroll
          for (int o = 8; o; o >>= 1) mx = fmaxf(mx, __shfl_xor(mx, o, 16));
          float sme = 0.f;
#pragma unroll
          for (int nf = 0; nf < 4; nf++) sme += (vv[nf] > -3.0e38f) ? __expf(vv[nf] - mx) : 0.f;
#pragma unroll
          for (int o = 8; o; o >>= 1) sme += __shfl_xor(sme, o, 16);
          if (cb == 0) { mred[row][wn] = mx; sred[row][wn] = sme; }
        }
      }
      __syncthreads();
      if (tid < 128) {
        float m0 = mred[tid][0], m1 = mred[tid][1];
        float M = fmaxf(m0, m1);
        float Ssum = sred[tid][0] * __expf(m0 - M) + sred[tid][1] * __expf(m1 - M);
        p.m_sb[tid * 96 + blk] = M;
        p.s_sb[tid * 96 + blk] = Ssum;
      }
    } else if (blk >= 158 && blk < 164) {
      int pr = blk - 158;
      ACC_INIT;
      gemm_pinB<16>(hnxt, Bpin, Ab0, Ab1, acc, wm, wn, lane, tid);
      if (pr == 0)
        mfma_epilogue(p.offo, 128, 0, 0, 128, nullptr, nullptr, p.off_base, acc, wm, wn, lane);
      else if (pr == 1)
        mfma_epilogue(p.awo, 128, 0, 0, 128, nullptr, nullptr, p.aw_base, acc, wm, wn, lane);
      else
        mfma_epilogue(p.hproj, 512, 0, (pr - 2) * 128, 512, p.hsb, nullptr, nullptr,
                      acc, wm, wn, lane);
    }
    grid.sync();

    // ---- P4: sample(t+1), 4 units per block ----
    if (t + 1 < NSTEP) {
#pragma unroll
      for (int i = 0; i < 4; i++)
        do_sample(p.value, p.offo, p.awo, p.hproj, 512, p.refp, p.vrat, p.ctxWT,
                  p.ctxb, p.alphaW, p.alphab, p.attnbf, blk * 4 + i, smp);
    }
    grid.sync();
  }
  if (orow >= 0) do_out(p.logits, p.m_sb, p.s_sb, p.outp, NSTEP - 1, orow, smo);
}

// ---------------- host launch ----------------
extern "C" void kernel_launch(void* const* d_in, const int* in_sizes, int n_in,
                              void* d_out, int out_size, void* d_ws, size_t ws_size,
                              hipStream_t stream) {
  const int* seq             = (const int*)d_in[0];
  const float* query         = (const float*)d_in[1];
  const float* refp          = (const float*)d_in[2];
  const float* enc           = (const float*)d_in[3];
  const float* vrat          = (const float*)d_in[4];
  const unsigned char* mask  = (const unsigned char*)d_in[5];
  const float* embedW        = (const float*)d_in[8];
  const float* logitW        = (const float*)d_in[9];
  const float* logitb        = (const float*)d_in[10];
  const float* Wih           = (const float*)d_in[11];
  const float* Whh           = (const float*)d_in[12];
  const float* valueW        = (const float*)d_in[13];
  const float* valueb        = (const float*)d_in[14];
  const float* offW          = (const float*)d_in[15];
  const float* offb          = (const float*)d_in[16];
  const float* awW           = (const float*)d_in[17];
  const float* awb           = (const float*)d_in[18];
  const float* ctxW          = (const float*)d_in[19];
  const float* ctxb          = (const float*)d_in[20];
  const float* hsW           = (const float*)d_in[21];
  const float* hsb           = (const float*)d_in[22];
  const float* alphaW        = (const float*)d_in[23];
  const float* alphab        = (const float*)d_in[24];

  char* wp = (char*)d_ws;
  auto alloc_f = [&](size_t n) { float* p = (float*)wp; wp += ((n * 4 + 255) / 256) * 256; return p; };
  auto alloc_u = [&](size_t n) { unsigned short* p = (unsigned short*)wp; wp += ((n * 2 + 255) / 256) * 256; return p; };

  float* value   = alloc_f((size_t)B_ * S_ * D_);
  float* logits  = alloc_f((size_t)BQ_ * V_);
  float* gpart   = alloc_f((size_t)4 * BQ_ * 2048);
  float* hproj   = alloc_f((size_t)BQ_ * D_);
  float* offo    = alloc_f((size_t)BQ_ * 128);
  float* awo     = alloc_f((size_t)BQ_ * 128);
  float* off_base= alloc_f((size_t)BQ_ * 128);
  float* aw_base = alloc_f((size_t)BQ_ * 128);
  float* c0      = alloc_f((size_t)BQ_ * D_);
  float* c1      = alloc_f((size_t)BQ_ * D_);
  float* ctxWT   = alloc_f((size_t)64 * 512);
  float* m_sb    = alloc_f((size_t)BQ_ * 96);
  float* s_sb    = alloc_f((size_t)BQ_ * 96);
  unsigned short* hbf0    = alloc_u((size_t)BQ_ * D_);
  unsigned short* hbf1    = alloc_u((size_t)BQ_ * D_);
  unsigned short* attnbf  = alloc_u((size_t)BQ_ * D_);
  unsigned short* qbf     = alloc_u((size_t)BQ_ * D_);
  unsigned short* xembbf  = alloc_u((size_t)NSTEP * BQ_ * D_);
  unsigned short* gates_base = alloc_u((size_t)NSTEP * BQ_ * 2048);
  unsigned short* logitWbf = alloc_u((size_t)V_ * D_);
  unsigned short* Wihbf    = alloc_u((size_t)2048 * 1536);
  unsigned short* Whhbf    = alloc_u((size_t)2048 * 512);
  unsigned short* offWbf   = alloc_u((size_t)128 * 1024);
  unsigned short* awWbf    = alloc_u((size_t)128 * 1024);
  unsigned short* hsWbf    = alloc_u((size_t)512 * 512);
  unsigned short* valueWbf = alloc_u((size_t)512 * 512);

  // one-time
  k_prep<<<11984, 256, 0, stream>>>(logitW, Wih, Whh, offW, awW, hsW, valueW, query, ctxW,
                                    seq, embedW,
                                    logitWbf, Wihbf, Whhbf, offWbf, awWbf, hsWbf,
                                    valueWbf, qbf, ctxWT, hbf0, c0, xembbf);
  k_value<<<480, 256, 0, stream>>>(enc, valueWbf, valueb, mask, value);
  k_qg<<<242, 256, 0, stream>>>(qbf, offWbf, offb, awWbf, awb, off_base, aw_base,
                                xembbf, Wihbf, gates_base);
  k_sample0<<<1024, 256, 0, stream>>>(value, off_base, aw_base, hsb, refp, vrat,
                                      ctxWT, ctxb, alphaW, alphab, attnbf);

  PArgs args;
  args.value = value; args.refp = refp; args.vrat = vrat; args.ctxWT = ctxWT;
  args.ctxb = ctxb; args.alphaW = alphaW; args.alphab = alphab;
  args.logitb = logitb; args.hsb = hsb; args.off_base = off_base; args.aw_base = aw_base;
  args.offo = offo; args.awo = awo; args.hproj = hproj; args.logits = logits;
  args.m_sb = m_sb; args.s_sb = s_sb; args.gpart = gpart; args.c0 = c0; args.c1 = c1;
  args.outp = (float*)d_out;
  args.logitWbf = logitWbf; args.Wihbf = Wihbf; args.Whhbf = Whhbf;
  args.offWbf = offWbf; args.awWbf = awWbf; args.hsWbf = hsWbf;
  args.gates_base = gates_base;
  args.hbf0 = hbf0; args.hbf1 = hbf1; args.attnbf = attnbf;

  void* kp[1] = {&args};
  hipError_t err = hipLaunchCooperativeKernel(reinterpret_cast<void*>(k_persist),
                                              dim3(256), dim3(256), kp, 0, stream);
  if (err != hipSuccess) {
    // fallback: proven R9 step loop
    unsigned short* hb[2] = {hbf0, hbf1};
    float* cb[2] = {c0, c1};
    float* outp = (float*)d_out;
    for (int t = 0; t < NSTEP; t++) {
      int cur = t & 1, nxt = cur ^ 1;
      k_lstm_gemm<<<dim3(16, 4), 256, 0, stream>>>(attnbf, hb[cur], Wihbf, Whhbf, gpart);
      k_cell<<<256, 256, 0, stream>>>(gpart, gates_base + (size_t)t * BQ_ * 2048,
                                      cb[cur], cb[nxt], hb[nxt]);
      k_logits_pre<<<NSLAB + 6, 256, 0, stream>>>(hb[nxt], logitWbf, logitb,
                                                  logits, m_sb, s_sb,
                                                  offWbf, awWbf, hsWbf, hsb,
                                                  off_base, aw_base, offo, awo, hproj);
      k_out_sample<<<128 + 1024, 256, 0, stream>>>(logits, m_sb, s_sb, outp, t,
                                                   value, offo, awo, hproj, refp, vrat,
                                                   ctxWT, ctxb, alphaW, alphab, attnbf);
    }
  }
}

// Round 12
// 1102.636 us; speedup vs baseline: 2.8912x; 2.8912x over previous
//
#include <hip/hip_runtime.h>

// ---- static problem config ----
#define B_ 4
#define Q_ 32
#define D_ 512
#define H_ 8
#define L_ 4
#define P_ 4
#define V_ 12000
#define T_ 16
#define HD_ 64
#define S_ 3840
#define BQ_ 128
#define NSTEP 15
#define NSLAB 94   // ceil(12000/128)
#define BSTR 520   // pinned-B LDS row stride (shorts)

typedef __attribute__((ext_vector_type(8))) short short8;
typedef __attribute__((ext_vector_type(4))) float f32x4;

__device__ inline unsigned short f2bf(float x) {
  union { float f; unsigned u; } v; v.f = x;
  unsigned u = v.u;
  unsigned r = (u + 0x7fffu + ((u >> 16) & 1u)) >> 16;  // RNE
  return (unsigned short)r;
}
__device__ inline float bf2f(unsigned short b) {
  union { unsigned u; float f; } v; v.u = ((unsigned)b) << 16; return v.f;
}
__device__ inline float fast_tanh(float x) {
  x = fminf(fmaxf(x, -15.f), 15.f);
  float e = __expf(2.f * x);
  return (e - 1.f) / (e + 1.f);
}
__device__ inline float sigmoidf_(float x) { return 1.f / (1.f + __expf(-x)); }

// ---------------- shared-memory structs ----------------
#define APAD 40
struct SmemGemm {            // double-buffered (step kernels), ~42.5 KB
  unsigned short As0[128 * APAD], Bs0[128 * APAD];
  unsigned short As1[128 * APAD], Bs1[128 * APAD];
};
struct SmemGemmS {           // single-buffered (one-time kernels), ~20 KB
  unsigned short As[128 * APAD], Bs[128 * APAD];
};
struct SmemSample {
  float ctx_s[16][HD_];
  float aw_s[16];
  float wgt_s[16];
  float wred[4][16];
};

// ---------------- GEMM common pieces ----------------
__device__ inline short8 cvt8(float4 v0, float4 v1) {
  short8 p;
  p[0] = (short)f2bf(v0.x); p[1] = (short)f2bf(v0.y);
  p[2] = (short)f2bf(v0.z); p[3] = (short)f2bf(v0.w);
  p[4] = (short)f2bf(v1.x); p[5] = (short)f2bf(v1.y);
  p[6] = (short)f2bf(v1.z); p[7] = (short)f2bf(v1.w);
  return p;
}

__device__ inline void mfma_step(const unsigned short* As, const unsigned short* Bs,
                                 f32x4 acc[4][4], int wm, int wn, int lane) {
  int r15 = lane & 15, koct = (lane >> 4) * 8;
  short8 a[4], b[4];
#pragma unroll
  for (int mf = 0; mf < 4; mf++)
    a[mf] = *(const short8*)(As + (wm * 64 + mf * 16 + r15) * APAD + koct);
#pragma unroll
  for (int nf = 0; nf < 4; nf++)
    b[nf] = *(const short8*)(Bs + (wn * 64 + nf * 16 + r15) * APAD + koct);
#pragma unroll
  for (int mf = 0; mf < 4; mf++)
#pragma unroll
    for (int nf = 0; nf < 4; nf++)
      acc[mf][nf] = __builtin_amdgcn_mfma_f32_16x16x32_bf16(a[mf], b[nf], acc[mf][nf], 0, 0, 0);
}

// Pipelined K-loop: double-buffered LDS, ONE sync/iter, register prefetch.
template <int NT, class FA, class FB>
__device__ inline void gemm_pipe(FA loadA, FB loadB, SmemGemm& sm,
                                 f32x4 acc[4][4], int wm, int wn, int lane, int tid) {
  int r = tid >> 2, ko = (tid & 3) * 8;
  short8 a0, a1, b0, b1;
  loadA(0, a0, a1); loadB(0, b0, b1);
#pragma unroll
  for (int t = 0; t < NT; t++) {
    unsigned short* As = (t & 1) ? sm.As1 : sm.As0;
    unsigned short* Bs = (t & 1) ? sm.Bs1 : sm.Bs0;
    *(short8*)(As + r * APAD + ko) = a0;
    *(short8*)(As + (r + 64) * APAD + ko) = a1;
    *(short8*)(Bs + r * APAD + ko) = b0;
    *(short8*)(Bs + (r + 64) * APAD + ko) = b1;
    short8 na0, na1, nb0, nb1;
    if (t + 1 < NT) { loadA(t + 1, na0, na1); loadB(t + 1, nb0, nb1); }
    __syncthreads();
    mfma_step(As, Bs, acc, wm, wn, lane);
    if (t + 1 < NT) { a0 = na0; a1 = na1; b0 = nb0; b1 = nb1; }
  }
}

// Single-buffered loop (one-time kernels)
template <int NT, class FA, class FB>
__device__ inline void gemm_simple(FA loadA, FB loadB, SmemGemmS& sm,
                                   f32x4 acc[4][4], int wm, int wn, int lane, int tid) {
  int r = tid >> 2, ko = (tid & 3) * 8;
#pragma unroll 2
  for (int t = 0; t < NT; t++) {
    short8 a0, a1, b0, b1;
    loadA(t, a0, a1); loadB(t, b0, b1);
    *(short8*)(sm.As + r * APAD + ko) = a0;
    *(short8*)(sm.As + (r + 64) * APAD + ko) = a1;
    *(short8*)(sm.Bs + r * APAD + ko) = b0;
    *(short8*)(sm.Bs + (r + 64) * APAD + ko) = b1;
    __syncthreads();
    mfma_step(sm.As, sm.Bs, acc, wm, wn, lane);
    __syncthreads();
  }
}

// Pinned-B K-loop: B lives in LDS (BSTR stride); A double-buffered, 1 sync/iter.
template <int NT>
__device__ inline void gemm_pinB(const unsigned short* __restrict__ Asrc,
                                 const unsigned short* Bpin,
                                 unsigned short* Ab0, unsigned short* Ab1,
                                 f32x4 acc[4][4], int wm, int wn, int lane, int tid) {
  int r = tid >> 2, ko = (tid & 3) * 8;
  int r15 = lane & 15, koct = (lane >> 4) * 8;
  short8 a0 = *(const short8*)(Asrc + (size_t)r * 512 + ko);
  short8 a1 = *(const short8*)(Asrc + (size_t)(r + 64) * 512 + ko);
#pragma unroll
  for (int t = 0; t < NT; t++) {
    unsigned short* Ab = (t & 1) ? Ab1 : Ab0;
    *(short8*)(Ab + r * APAD + ko) = a0;
    *(short8*)(Ab + (r + 64) * APAD + ko) = a1;
    short8 na0, na1;
    if (t + 1 < NT) {
      na0 = *(const short8*)(Asrc + (size_t)r * 512 + (t + 1) * 32 + ko);
      na1 = *(const short8*)(Asrc + (size_t)(r + 64) * 512 + (t + 1) * 32 + ko);
    }
    __syncthreads();
    short8 af[4], bfr[4];
#pragma unroll
    for (int mf = 0; mf < 4; mf++)
      af[mf] = *(const short8*)(Ab + (wm * 64 + mf * 16 + r15) * APAD + koct);
#pragma unroll
    for (int nf = 0; nf < 4; nf++)
      bfr[nf] = *(const short8*)(Bpin + (size_t)(wn * 64 + nf * 16 + r15) * BSTR + t * 32 + koct);
#pragma unroll
    for (int mf = 0; mf < 4; mf++)
#pragma unroll
      for (int nf = 0; nf < 4; nf++)
        acc[mf][nf] = __builtin_amdgcn_mfma_f32_16x16x32_bf16(af[mf], bfr[nf], acc[mf][nf], 0, 0, 0);
    if (t + 1 < NT) { a0 = na0; a1 = na1; }
  }
}

// D layout (HW-verified m89): col = lane&15, row = (lane>>4)*4 + j
__device__ inline void mfma_epilogue(float* __restrict__ out, int ldo, int m0, int n0,
                                     int Nmax, const float* __restrict__ bias,
                                     const unsigned char* __restrict__ mask,
                                     const float* __restrict__ base,
                                     f32x4 acc[4][4], int wm, int wn, int lane) {
  int rb = (lane >> 4) * 4, cb = lane & 15;
#pragma unroll
  for (int nf = 0; nf < 4; nf++) {
    int col = n0 + wn * 64 + nf * 16 + cb;
    if (col >= Nmax) continue;
    float bv = bias ? bias[col] : 0.f;
#pragma unroll
    for (int mf = 0; mf < 4; mf++) {
#pragma unroll
      for (int j = 0; j < 4; j++) {
        int row = m0 + wm * 64 + mf * 16 + rb + j;
        float v = acc[mf][nf][j] + bv;
        if (base) v += base[(size_t)row * ldo + col];
        if (mask && mask[row]) v = 0.f;
        out[(size_t)row * ldo + col] = v;
      }
    }
  }
}

__device__ inline void mfma_epilogue_bf16(unsigned short* __restrict__ out, int ldo, int n0,
                                          f32x4 acc[4][4], int wm, int wn, int lane) {
  int rb = (lane >> 4) * 4, cb = lane & 15;
#pragma unroll
  for (int nf = 0; nf < 4; nf++) {
    int col = n0 + wn * 64 + nf * 16 + cb;
#pragma unroll
    for (int mf = 0; mf < 4; mf++) {
#pragma unroll
      for (int j = 0; j < 4; j++) {
        int row = wm * 64 + mf * 16 + rb + j;
        out[(size_t)row * ldo + col] = f2bf(acc[mf][nf][j]);
      }
    }
  }
}

#define ACC_INIT f32x4 acc[4][4]; { f32x4 z = {0.f,0.f,0.f,0.f}; \
  _Pragma("unroll") for (int i_=0;i_<4;i_++) _Pragma("unroll") for (int j_=0;j_<4;j_++) acc[i_][j_]=z; }

// ================= kernels =================

// one-time: weight converts (Wih/Whh row-PERMUTED) + inits + ctxW transpose + embed gather
__global__ __launch_bounds__(256) void k_prep(const float* __restrict__ logitW,
    const float* __restrict__ Wih, const float* __restrict__ Whh,
    const float* __restrict__ offW, const float* __restrict__ awW,
    const float* __restrict__ hsW, const float* __restrict__ valueW,
    const float* __restrict__ query, const float* __restrict__ ctxW,
    const int* __restrict__ seq, const float* __restrict__ embedW,
    unsigned short* __restrict__ logitWbf, unsigned short* __restrict__ Wihbf,
    unsigned short* __restrict__ Whhbf, unsigned short* __restrict__ offWbf,
    unsigned short* __restrict__ awWbf, unsigned short* __restrict__ hsWbf,
    unsigned short* __restrict__ valueWbf, unsigned short* __restrict__ qbf,
    float* __restrict__ ctxWT, unsigned short* __restrict__ hall, float* __restrict__ c0,
    unsigned short* __restrict__ xembbf) {
  int gi = blockIdx.x * 256 + threadIdx.x;
  const int e0 = 1536000, e1 = e0 + 786432, e2 = e1 + 262144, e3 = e2 + 32768,
            e4 = e3 + 32768, e5 = e4 + 65536, e6 = e5 + 65536, e7 = e6 + 16384;
  const int e8 = e7 + 16384, e9 = e8 + 8192, e10 = e9 + 245760;
  if (gi < e7) {
    const float* src; unsigned short* dst; int lo, dsti;
    if (gi < e0)      { src = logitW; dst = logitWbf; lo = gi; dsti = lo; }
    else if (gi < e1) {
      src = Wih; dst = Wihbf; lo = gi - e0;
      int row = lo / 384, c4 = lo - row * 384;
      int g = row >> 9, d = row & 511, n = d >> 5, rr = d & 31;
      dsti = (n * 128 + g * 32 + rr) * 384 + c4;
    }
    else if (gi < e2) {
      src = Whh; dst = Whhbf; lo = gi - e1;
      int row = lo >> 7, c4 = lo & 127;
      int g = row >> 9, d = row & 511, n = d >> 5, rr = d & 31;
      dsti = (n * 128 + g * 32 + rr) * 128 + c4;
    }
    else if (gi < e3) { src = offW;   dst = offWbf;   lo = gi - e2; dsti = lo; }
    else if (gi < e4) { src = awW;    dst = awWbf;    lo = gi - e3; dsti = lo; }
    else if (gi < e5) { src = hsW;    dst = hsWbf;    lo = gi - e4; dsti = lo; }
    else if (gi < e6) { src = valueW; dst = valueWbf; lo = gi - e5; dsti = lo; }
    else              { src = query;  dst = qbf;      lo = gi - e6; dsti = lo; }
    float4 v = ((const float4*)src)[lo];
    ushort4 o;
    o.x = f2bf(v.x); o.y = f2bf(v.y); o.z = f2bf(v.z); o.w = f2bf(v.w);
    ((ushort4*)dst)[dsti] = o;
  } else if (gi < e8) {
    int i = gi - e7;
    ushort4 z4; z4.x = 0; z4.y = 0; z4.z = 0; z4.w = 0;
    ((ushort4*)hall)[i] = z4;            // hall slot 0 = h_0 = 0
    float4 z = {0.f, 0.f, 0.f, 0.f};
    ((float4*)c0)[i] = z;
  } else if (gi < e9) {
    int i = gi - e8;
    int k = i >> 7, d4 = i & 127;
    float4 o;
    o.x = ctxW[(d4 * 4 + 0) * 64 + k];
    o.y = ctxW[(d4 * 4 + 1) * 64 + k];
    o.z = ctxW[(d4 * 4 + 2) * 64 + k];
    o.w = ctxW[(d4 * 4 + 3) * 64 + k];
    ((float4*)ctxWT)[k * 128 + d4] = o;
  } else if (gi < e10) {
    int i = gi - e9;
    int row = i >> 7, d4 = i & 127;
    int t = row >> 7, bq = row & 127;
    int tok = seq[bq * T_ + t];
    float4 v = ((const float4*)embedW)[(size_t)tok * 128 + d4];
    ushort4 o;
    o.x = f2bf(v.x); o.y = f2bf(v.y); o.z = f2bf(v.z); o.w = f2bf(v.w);
    ((ushort4*)xembbf)[(size_t)row * 128 + d4] = o;
  }
}

// one-time: value = enc @ valueW^T + b (masked), 480 blocks XCD-swizzled
__global__ __launch_bounds__(256) void k_value(const float* __restrict__ enc,
    const unsigned short* __restrict__ valueWbf, const float* __restrict__ valueb,
    const unsigned char* __restrict__ mask, float* __restrict__ value) {
  __shared__ SmemGemmS sm;
  int blk = blockIdx.x;
  int xcd = blk & 7, j = blk >> 3;
  int m0 = (xcd * 15 + (j >> 2)) * 128, n0 = (j & 3) * 128;
  int tid = threadIdx.x;
  int lane = tid & 63, w = tid >> 6, wm = w >> 1, wn = w & 1;
  int r = tid >> 2, ko = (tid & 3) * 8;
  ACC_INIT;
  gemm_simple<16>(
    [&](int t, short8& x, short8& y) {
      const float4* s0 = (const float4*)(enc + (size_t)(m0 + r) * 512 + t * 32 + ko);
      const float4* s1 = (const float4*)(enc + (size_t)(m0 + r + 64) * 512 + t * 32 + ko);
      x = cvt8(s0[0], s0[1]); y = cvt8(s1[0], s1[1]);
    },
    [&](int t, short8& x, short8& y) {
      x = *(const short8*)(valueWbf + (size_t)(n0 + r) * 512 + t * 32 + ko);
      y = *(const short8*)(valueWbf + (size_t)(n0 + r + 64) * 512 + t * 32 + ko);
    },
    sm, acc, wm, wn, lane, tid);
  mfma_epilogue(value, 512, m0, n0, 512, valueb, mask, nullptr, acc, wm, wn, lane);
}

// one-time: qproj (2 blocks) + gates_pre (240 blocks, XCD-swizzled, permuted Wih)
__global__ __launch_bounds__(256) void k_qg(const unsigned short* __restrict__ qbf,
    const unsigned short* __restrict__ offWbf, const float* __restrict__ offb,
    const unsigned short* __restrict__ awWbf, const float* __restrict__ awb,
    float* __restrict__ off_base, float* __restrict__ aw_base,
    const unsigned short* __restrict__ xembbf,
    const unsigned short* __restrict__ Wihbf, unsigned short* __restrict__ gates_base) {
  __shared__ SmemGemmS sm;
  int blk = blockIdx.x;
  int tid = threadIdx.x;
  int lane = tid & 63, w = tid >> 6, wm = w >> 1, wn = w & 1;
  int r = tid >> 2, ko = (tid & 3) * 8;
  if (blk < 2) {
    const unsigned short* Bw = blk ? awWbf : offWbf;
    const float* bias = blk ? awb : offb;
    float* out = blk ? aw_base : off_base;
    ACC_INIT;
    gemm_simple<16>(
      [&](int t, short8& x, short8& y) {
        x = *(const short8*)(qbf + (size_t)r * 512 + t * 32 + ko);
        y = *(const short8*)(qbf + (size_t)(r + 64) * 512 + t * 32 + ko);
      },
      [&](int t, short8& x, short8& y) {
        x = *(const short8*)(Bw + (size_t)r * 1024 + 512 + t * 32 + ko);
        y = *(const short8*)(Bw + (size_t)(r + 64) * 1024 + 512 + t * 32 + ko);
      },
      sm, acc, wm, wn, lane, tid);
    mfma_epilogue(out, 128, 0, 0, 128, bias, nullptr, nullptr, acc, wm, wn, lane);
  } else {
    int g = blk - 2;
    int xcd = g & 7, j = g >> 3;
    int n0 = (xcd * 2 + (j >= 15)) * 128;
    int st = (j >= 15) ? (j - 15) : j;
    const unsigned short* xa = xembbf + (size_t)(st * 128) * 512;
    ACC_INIT;
    gemm_simple<32>(
      [&](int t, short8& x, short8& y) {
        const unsigned short* src = (t < 16) ? xa : qbf;
        int kk = (t < 16) ? t * 32 : (t - 16) * 32;
        x = *(const short8*)(src + (size_t)r * 512 + kk + ko);
        y = *(const short8*)(src + (size_t)(r + 64) * 512 + kk + ko);
      },
      [&](int t, short8& x, short8& y) {
        int kk = (t < 16) ? t * 32 : 1024 + (t - 16) * 32;
        x = *(const short8*)(Wihbf + (size_t)(n0 + r) * 1536 + kk + ko);
        y = *(const short8*)(Wihbf + (size_t)(n0 + r + 64) * 1536 + kk + ko);
      },
      sm, acc, wm, wn, lane, tid);
    mfma_epilogue_bf16(gates_base + (size_t)st * 128 * 2048, 2048, n0, acc, wm, wn, lane);
  }
}

// per-step: deformable sampling + tanh additive attention (1024 blocks)
__global__ __launch_bounds__(256) void k_sample(const float* __restrict__ value,
    const float* __restrict__ off_src, const float* __restrict__ aw_src,
    const float* __restrict__ hp_src, int hstride,
    const float* __restrict__ refp, const float* __restrict__ vrat,
    const float* __restrict__ ctxWT, const float* __restrict__ ctxb,
    const float* __restrict__ alphaW, const float* __restrict__ alphab,
    unsigned short* __restrict__ attnbf) {
  __shared__ SmemSample sm;
  int blk = blockIdx.x;
  int bq = blk >> 3, h = blk & 7;
  int b = bq >> 5;
  int tid = threadIdx.x;
  int lane = tid & 63, wid = tid >> 6;

  if (tid < 16) {
    float v = aw_src[bq * 128 + h * 16 + tid];
    float m = v;
#pragma unroll
    for (int o = 8; o; o >>= 1) m = fmaxf(m, __shfl_xor(m, o, 16));
    float e = __expf(v - m);
    float s = e;
#pragma unroll
    for (int o = 8; o; o >>= 1) s += __shfl_xor(s, o, 16);
    sm.aw_s[tid] = e / s;
  }
  __syncthreads();

  {
    const int TSv[4] = {2048, 1024, 512, 256};
    const int LSv[4] = {0, 2048, 3072, 3584};
    float ref = refp[bq];
    int hd = tid & 63;
#pragma unroll
    for (int pp = 0; pp < 4; pp++) {
      int p = pp * 4 + (tid >> 6);
      int l = p >> 2;
      int Tl = TSv[l];
      float off = off_src[bq * 128 + h * 16 + p];
      float loc = ref * vrat[b * L_ + l] + off / (float)Tl;
      float x = loc * (float)Tl - 0.5f;
      float x0 = floorf(x);
      float wf = x - x0;
      int i0 = (int)x0;
      const float* vb = value + ((size_t)(b * S_ + LSv[l]) * D_) + h * HD_ + hd;
      float v0 = (i0 >= 0 && i0 < Tl) ? vb[(size_t)i0 * D_] : 0.f;
      float v1 = (i0 + 1 >= 0 && i0 + 1 < Tl) ? vb[(size_t)(i0 + 1) * D_] : 0.f;
      sm.ctx_s[p][hd] = (v0 * (1.f - wf) + v1 * wf) * sm.aw_s[p];
    }
  }
  __syncthreads();

  float2 sacc[16];
#pragma unroll
  for (int p = 0; p < 16; p++) { sacc[p].x = 0.f; sacc[p].y = 0.f; }
  for (int k4 = 0; k4 < 16; k4++) {
    float2 wv[4];
#pragma unroll
    for (int kk = 0; kk < 4; kk++)
      wv[kk] = *(const float2*)(ctxWT + (k4 * 4 + kk) * 512 + 2 * tid);
#pragma unroll
    for (int p = 0; p < 16; p++) {
      float4 c = *(const float4*)(&sm.ctx_s[p][k4 * 4]);
      sacc[p].x += c.x * wv[0].x + c.y * wv[1].x + c.z * wv[2].x + c.w * wv[3].x;
      sacc[p].y += c.x * wv[0].y + c.y * wv[1].y + c.z * wv[2].y + c.w * wv[3].y;
    }
  }

  {
    float2 cb = *(const float2*)(ctxb + 2 * tid);
    float2 hp = *(const float2*)(hp_src + (size_t)hstride * bq + 2 * tid);
    float2 al = *(const float2*)(alphaW + 2 * tid);
    float part[16];
#pragma unroll
    for (int p = 0; p < 16; p++)
      part[p] = al.x * fast_tanh(sacc[p].x + cb.x + hp.x) +
                al.y * fast_tanh(sacc[p].y + cb.y + hp.y);
#pragma unroll
    for (int o = 32; o; o >>= 1)
#pragma unroll
      for (int p = 0; p < 16; p++) part[p] += __shfl_xor(part[p], o, 64);
    if (lane == 0)
#pragma unroll
      for (int p = 0; p < 16; p++) sm.wred[wid][p] = part[p];
  }
  __syncthreads();
  if (tid < 16) {
    float v = sm.wred[0][tid] + sm.wred[1][tid] + sm.wred[2][tid] + sm.wred[3][tid] + alphab[0];
    float m = v;
#pragma unroll
    for (int o = 8; o; o >>= 1) m = fmaxf(m, __shfl_xor(m, o, 16));
    float e = __expf(v - m);
    float s = e;
#pragma unroll
    for (int o = 8; o; o >>= 1) s += __shfl_xor(s, o, 16);
    sm.wgt_s[tid] = e / s;
  }
  __syncthreads();
  if (tid < 64) {
    float a = 0.f;
#pragma unroll
    for (int pi = 0; pi < 16; pi++) a += sm.wgt_s[pi] * sm.ctx_s[pi][tid];
    attnbf[bq * D_ + h * HD_ + tid] = f2bf(a);
  }
}

// per-step LSTM gates, split-K: K=1024 over [attn|h], 4 chunks (permuted weights)
__global__ __launch_bounds__(256) void k_lstm_gemm(
    const unsigned short* __restrict__ attnbf, const unsigned short* __restrict__ hcur,
    const unsigned short* __restrict__ Wihbf, const unsigned short* __restrict__ Whhbf,
    float* __restrict__ gpart) {
  __shared__ SmemGemm sm;
  int tid = threadIdx.x;
  int lane = tid & 63, w = tid >> 6, wm = w >> 1, wn = w & 1;
  int r = tid >> 2, ko = (tid & 3) * 8;
  int n0 = blockIdx.x * 128;
  int kc = blockIdx.y;
  const unsigned short* Asrc = (kc < 2) ? (attnbf + kc * 256) : (hcur + (kc - 2) * 256);
  const unsigned short* Bsrc = (kc < 2) ? (Wihbf + (size_t)n0 * 1536 + 512 + kc * 256)
                                        : (Whhbf + (size_t)n0 * 512 + (kc - 2) * 256);
  int ldB = (kc < 2) ? 1536 : 512;
  ACC_INIT;
  gemm_pipe<8>(
    [&](int t, short8& x, short8& y) {
      x = *(const short8*)(Asrc + (size_t)r * 512 + t * 32 + ko);
      y = *(const short8*)(Asrc + (size_t)(r + 64) * 512 + t * 32 + ko);
    },
    [&](int t, short8& x, short8& y) {
      x = *(const short8*)(Bsrc + (size_t)r * ldB + t * 32 + ko);
      y = *(const short8*)(Bsrc + (size_t)(r + 64) * ldB + t * 32 + ko);
    },
    sm, acc, wm, wn, lane, tid);
  mfma_epilogue(gpart + (size_t)kc * 262144, 2048, 0, n0, 2048,
                nullptr, nullptr, nullptr, acc, wm, wn, lane);
}

// LSTM cell: fused split-K reduce + base add + nonlinearity (permuted gate columns)
__global__ __launch_bounds__(256) void k_cell(const float* __restrict__ gpart,
    const unsigned short* __restrict__ gbase_t,
    const float* __restrict__ c, float* __restrict__ cn, unsigned short* __restrict__ hout) {
  int idx = blockIdx.x * 256 + threadIdx.x;
  int bq = idx >> 9, d = idx & 511;
  int n = d >> 5, rr = d & 31;
  size_t rowoff = (size_t)bq * 2048 + n * 128 + rr;
  float g4[4];
#pragma unroll
  for (int gate = 0; gate < 4; gate++) {
    size_t off = rowoff + gate * 32;
    float s = bf2f(gbase_t[off]);
    s += gpart[off] + gpart[262144 + off] + gpart[2 * 262144 + off] + gpart[3 * 262144 + off];
    g4[gate] = s;
  }
  float cc = c[idx];
  float c2 = sigmoidf_(g4[1]) * cc + sigmoidf_(g4[0]) * fast_tanh(g4[2]);
  float h2 = sigmoidf_(g4[3]) * fast_tanh(c2);
  cn[idx] = c2;
  hout[idx] = f2bf(h2);
}

// per-step projections: off/aw (h half) + hproj; 6 blocks
__global__ __launch_bounds__(256) void k_pre(const unsigned short* __restrict__ hbf,
    const unsigned short* __restrict__ offWbf, const unsigned short* __restrict__ awWbf,
    const unsigned short* __restrict__ hsWbf, const float* __restrict__ hsb,
    const float* __restrict__ off_base, const float* __restrict__ aw_base,
    float* __restrict__ offo, float* __restrict__ awo, float* __restrict__ hpo) {
  __shared__ SmemGemm sm;
  int blk = blockIdx.x;
  const unsigned short* Bw; const float* bias; const float* base;
  float* out; int ldkB, n0, ldo;
  if (blk == 0)      { Bw = offWbf; bias = nullptr; base = off_base; out = offo; ldkB = 1024; n0 = 0; ldo = 128; }
  else if (blk == 1) { Bw = awWbf;  bias = nullptr; base = aw_base;  out = awo;  ldkB = 1024; n0 = 0; ldo = 128; }
  else { Bw = hsWbf; bias = hsb; base = nullptr; out = hpo; ldkB = 512; n0 = (blk - 2) * 128; ldo = 512; }
  int tid = threadIdx.x;
  int lane = tid & 63, w = tid >> 6, wm = w >> 1, wn = w & 1;
  int r = tid >> 2, ko = (tid & 3) * 8;
  ACC_INIT;
  gemm_pipe<16>(
    [&](int t, short8& x, short8& y) {
      x = *(const short8*)(hbf + (size_t)r * 512 + t * 32 + ko);
      y = *(const short8*)(hbf + (size_t)(r + 64) * 512 + t * 32 + ko);
    },
    [&](int t, short8& x, short8& y) {
      x = *(const short8*)(Bw + (size_t)(n0 + r) * ldkB + t * 32 + ko);
      y = *(const short8*)(Bw + (size_t)(n0 + r + 64) * ldkB + t * 32 + ko);
    },
    sm, acc, wm, wn, lane, tid);
  mfma_epilogue(out, ldo, 0, n0, ldo, bias, nullptr, base, acc, wm, wn, lane);
}

// batched logits for ALL steps: 188 blocks = 94 slabs x 2 t-halves.
// Each block pins its logitW slab in LDS ONCE, then loops its steps.
// Writes raw logits+bias directly into d_out + per-(t,row) slab partials.
__global__ void __launch_bounds__(256, 1) k_logits_all(
    const unsigned short* __restrict__ logitWbf, const float* __restrict__ logitb,
    const unsigned short* __restrict__ hall, float* __restrict__ outp,
    float* __restrict__ m_sb, float* __restrict__ s_sb) {
  __shared__ unsigned short Bpin[128 * BSTR];   // 133120 B
  __shared__ unsigned short Ab[2][128 * APAD];  // 20480 B
  __shared__ float mred[128][2], sred[128][2];  // 2048 B
  int blk = blockIdx.x, tid = threadIdx.x;
  int slab = blk >> 1, thalf = blk & 1;
  int n0 = slab * 128;
  int lane = tid & 63, w = tid >> 6, wm = w >> 1, wn = w & 1;
  int r = tid >> 2, kb = (tid & 3) * 8;

  // pin slab
#pragma unroll
  for (int half = 0; half < 2; half++) {
    int row = r + half * 64;
    bool ok = (n0 + row) < V_;
    for (int kk = kb; kk < 512; kk += 32) {
      short8 v = {0, 0, 0, 0, 0, 0, 0, 0};
      if (ok) v = *(const short8*)(logitWbf + (size_t)(n0 + row) * 512 + kk);
      *(short8*)(Bpin + (size_t)row * BSTR + kk) = v;
    }
  }
  __syncthreads();

  int t0 = thalf ? 8 : 0, t1 = thalf ? NSTEP : 8;
  for (int t = t0; t < t1; t++) {
    const unsigned short* hn = hall + (size_t)(t + 1) * 65536;
    ACC_INIT;
    gemm_pinB<16>(hn, Bpin, Ab[0], Ab[1], acc, wm, wn, lane, tid);
    // epilogue: write raw logits to d_out slice + per-row slab (max, expsum)
    int rb = (lane >> 4) * 4, cb = lane & 15;
#pragma unroll
    for (int mf = 0; mf < 4; mf++) {
#pragma unroll
      for (int j = 0; j < 4; j++) {
        int row = wm * 64 + mf * 16 + rb + j;
        float vv[4];
        float mx = -3.4e38f;
#pragma unroll
        for (int nf = 0; nf < 4; nf++) {
          int col = n0 + wn * 64 + nf * 16 + cb;
          bool ok = col < V_;
          float v = ok ? (acc[mf][nf][j] + logitb[col]) : -3.4e38f;
          if (ok) outp[((size_t)row * NSTEP + t) * V_ + col] = v;
          vv[nf] = v;
          mx = fmaxf(mx, v);
        }
#pragma unroll
        for (int o = 8; o; o >>= 1) mx = fmaxf(mx, __shfl_xor(mx, o, 16));
        float sme = 0.f;
#pragma unroll
        for (int nf = 0; nf < 4; nf++) sme += (vv[nf] > -3.0e38f) ? __expf(vv[nf] - mx) : 0.f;
#pragma unroll
        for (int o = 8; o; o >>= 1) sme += __shfl_xor(sme, o, 16);
        if (cb == 0) { mred[row][wn] = mx; sred[row][wn] = sme; }
      }
    }
    __syncthreads();
    if (tid < 128) {
      float m0 = mred[tid][0], m1 = mred[tid][1];
      float M = fmaxf(m0, m1);
      float Ssum = sred[tid][0] * __expf(m0 - M) + sred[tid][1] * __expf(m1 - M);
      m_sb[((size_t)t * 128 + tid) * 96 + slab] = M;
      s_sb[((size_t)t * 128 + tid) * 96 + slab] = Ssum;
    }
    __syncthreads();
  }
}

// final: per (t,row) combine partials -> lse, subtract in-place in d_out
__global__ __launch_bounds__(256) void k_out_all(const float* __restrict__ m_sb,
    const float* __restrict__ s_sb, float* __restrict__ outp) {
  __shared__ float ms[NSLAB], ss[NSLAB];
  __shared__ float lse_s;
  int blk = blockIdx.x;                 // 1920 = 15*128
  int t = blk >> 7, row = blk & 127;
  int tid = threadIdx.x;
  size_t pbase = ((size_t)t * 128 + row) * 96;
  if (tid < NSLAB) { ms[tid] = m_sb[pbase + tid]; ss[tid] = s_sb[pbase + tid]; }
  __syncthreads();
  if (tid < 64) {
    float m = -3.4e38f, s = 0.f;
    for (int i = tid; i < NSLAB; i += 64) {
      float mi = ms[i], si = ss[i];
      float M = fmaxf(m, mi);
      s = s * __expf(m - M) + si * __expf(mi - M);
      m = M;
    }
#pragma unroll
    for (int o = 32; o; o >>= 1) {
      float mo = __shfl_xor(m, o, 64), so = __shfl_xor(s, o, 64);
      float M = fmaxf(m, mo);
      s = s * __expf(m - M) + so * __expf(mo - M);
      m = M;
    }
    if (tid == 0) lse_s = m + __logf(s);
  }
  __syncthreads();
  float lse = lse_s;
  float4* op = (float4*)(outp + ((size_t)row * NSTEP + t) * V_);
  for (int i = tid; i < V_ / 4; i += 256) {
    float4 v = op[i];
    v.x -= lse; v.y -= lse; v.z -= lse; v.w -= lse;
    op[i] = v;
  }
}

// ---------------- host launch ----------------
extern "C" void kernel_launch(void* const* d_in, const int* in_sizes, int n_in,
                              void* d_out, int out_size, void* d_ws, size_t ws_size,
                              hipStream_t stream) {
  const int* seq             = (const int*)d_in[0];
  const float* query         = (const float*)d_in[1];
  const float* refp          = (const float*)d_in[2];
  const float* enc           = (const float*)d_in[3];
  const float* vrat          = (const float*)d_in[4];
  const unsigned char* mask  = (const unsigned char*)d_in[5];
  const float* embedW        = (const float*)d_in[8];
  const float* logitW        = (const float*)d_in[9];
  const float* logitb        = (const float*)d_in[10];
  const float* Wih           = (const float*)d_in[11];
  const float* Whh           = (const float*)d_in[12];
  const float* valueW        = (const float*)d_in[13];
  const float* valueb        = (const float*)d_in[14];
  const float* offW          = (const float*)d_in[15];
  const float* offb          = (const float*)d_in[16];
  const float* awW           = (const float*)d_in[17];
  const float* awb           = (const float*)d_in[18];
  const float* ctxW          = (const float*)d_in[19];
  const float* ctxb          = (const float*)d_in[20];
  const float* hsW           = (const float*)d_in[21];
  const float* hsb           = (const float*)d_in[22];
  const float* alphaW        = (const float*)d_in[23];
  const float* alphab        = (const float*)d_in[24];

  char* wp = (char*)d_ws;
  auto alloc_f = [&](size_t n) { float* p = (float*)wp; wp += ((n * 4 + 255) / 256) * 256; return p; };
  auto alloc_u = [&](size_t n) { unsigned short* p = (unsigned short*)wp; wp += ((n * 2 + 255) / 256) * 256; return p; };

  float* value   = alloc_f((size_t)B_ * S_ * D_);
  float* gpart   = alloc_f((size_t)4 * BQ_ * 2048);
  float* hproj   = alloc_f((size_t)BQ_ * D_);
  float* offo    = alloc_f((size_t)BQ_ * 128);
  float* awo     = alloc_f((size_t)BQ_ * 128);
  float* off_base= alloc_f((size_t)BQ_ * 128);
  float* aw_base = alloc_f((size_t)BQ_ * 128);
  float* c0      = alloc_f((size_t)BQ_ * D_);
  float* c1      = alloc_f((size_t)BQ_ * D_);
  float* ctxWT   = alloc_f((size_t)64 * 512);
  float* m_sb    = alloc_f((size_t)NSTEP * BQ_ * 96);
  float* s_sb    = alloc_f((size_t)NSTEP * BQ_ * 96);
  unsigned short* hall    = alloc_u((size_t)(NSTEP + 1) * BQ_ * D_);  // h_0..h_15
  unsigned short* attnbf  = alloc_u((size_t)BQ_ * D_);
  unsigned short* qbf     = alloc_u((size_t)BQ_ * D_);
  unsigned short* xembbf  = alloc_u((size_t)NSTEP * BQ_ * D_);
  unsigned short* gates_base = alloc_u((size_t)NSTEP * BQ_ * 2048);
  unsigned short* logitWbf = alloc_u((size_t)V_ * D_);
  unsigned short* Wihbf    = alloc_u((size_t)2048 * 1536);
  unsigned short* Whhbf    = alloc_u((size_t)2048 * 512);
  unsigned short* offWbf   = alloc_u((size_t)128 * 1024);
  unsigned short* awWbf    = alloc_u((size_t)128 * 1024);
  unsigned short* hsWbf    = alloc_u((size_t)512 * 512);
  unsigned short* valueWbf = alloc_u((size_t)512 * 512);

  // one-time
  k_prep<<<11984, 256, 0, stream>>>(logitW, Wih, Whh, offW, awW, hsW, valueW, query, ctxW,
                                    seq, embedW,
                                    logitWbf, Wihbf, Whhbf, offWbf, awWbf, hsWbf,
                                    valueWbf, qbf, ctxWT, hall, c0, xembbf);
  k_value<<<480, 256, 0, stream>>>(enc, valueWbf, valueb, mask, value);
  k_qg<<<242, 256, 0, stream>>>(qbf, offWbf, offb, awWbf, awb, off_base, aw_base,
                                xembbf, Wihbf, gates_base);

  float* cb[2] = {c0, c1};
  float* outp = (float*)d_out;

  // recurrence loop: only small kernels on the critical chain
  for (int t = 0; t < NSTEP; t++) {
    const unsigned short* hcur = hall + (size_t)t * BQ_ * D_;
    unsigned short* hnxt = hall + (size_t)(t + 1) * BQ_ * D_;
    if (t == 0)
      k_sample<<<1024, 256, 0, stream>>>(value, off_base, aw_base, hsb, 0, refp, vrat,
                                         ctxWT, ctxb, alphaW, alphab, attnbf);
    else
      k_sample<<<1024, 256, 0, stream>>>(value, offo, awo, hproj, 512, refp, vrat,
                                         ctxWT, ctxb, alphaW, alphab, attnbf);
    k_lstm_gemm<<<dim3(16, 4), 256, 0, stream>>>(attnbf, hcur, Wihbf, Whhbf, gpart);
    k_cell<<<256, 256, 0, stream>>>(gpart, gates_base + (size_t)t * BQ_ * 2048,
                                    cb[t & 1], cb[(t + 1) & 1], hnxt);
    if (t + 1 < NSTEP)
      k_pre<<<6, 256, 0, stream>>>(hnxt, offWbf, awWbf, hsWbf, hsb,
                                   off_base, aw_base, offo, awo, hproj);
  }

  // batched logits (LDS-pinned weights, read once) + final lse subtract
  k_logits_all<<<2 * NSLAB, 256, 0, stream>>>(logitWbf, logitb, hall, outp, m_sb, s_sb);
  k_out_all<<<NSTEP * BQ_, 256, 0, stream>>>(m_sb, s_sb, outp);
}

// Round 13
// 1006.609 us; speedup vs baseline: 3.1670x; 1.0954x over previous
//
#include <hip/hip_runtime.h>

// ---- static problem config ----
#define B_ 4
#define Q_ 32
#define D_ 512
#define H_ 8
#define L_ 4
#define P_ 4
#define V_ 12000
#define T_ 16
#define HD_ 64
#define S_ 3840
#define BQ_ 128
#define NSTEP 15
#define NSLAB 94   // ceil(12000/128)

typedef __attribute__((ext_vector_type(8))) short short8;
typedef __attribute__((ext_vector_type(4))) float f32x4;

__device__ inline unsigned short f2bf(float x) {
  union { float f; unsigned u; } v; v.f = x;
  unsigned u = v.u;
  unsigned r = (u + 0x7fffu + ((u >> 16) & 1u)) >> 16;  // RNE
  return (unsigned short)r;
}
__device__ inline float bf2f(unsigned short b) {
  union { unsigned u; float f; } v; v.u = ((unsigned)b) << 16; return v.f;
}
__device__ inline float fast_tanh(float x) {
  x = fminf(fmaxf(x, -15.f), 15.f);
  float e = __expf(2.f * x);
  return (e - 1.f) / (e + 1.f);
}
__device__ inline float sigmoidf_(float x) { return 1.f / (1.f + __expf(-x)); }

// ---------------- shared-memory structs ----------------
#define APAD 40
struct SmemGemm {            // double-buffered, ~40 KB
  unsigned short As0[128 * APAD], Bs0[128 * APAD];
  unsigned short As1[128 * APAD], Bs1[128 * APAD];
};
struct SmemGemmS {           // single-buffered (one-time kernels), ~20 KB
  unsigned short As[128 * APAD], Bs[128 * APAD];
};
struct SmemSample {
  float ctx_s[16][HD_];
  float aw_s[16];
  float wgt_s[16];
  float wred[4][16];
};

// ---------------- GEMM common pieces ----------------
__device__ inline short8 cvt8(float4 v0, float4 v1) {
  short8 p;
  p[0] = (short)f2bf(v0.x); p[1] = (short)f2bf(v0.y);
  p[2] = (short)f2bf(v0.z); p[3] = (short)f2bf(v0.w);
  p[4] = (short)f2bf(v1.x); p[5] = (short)f2bf(v1.y);
  p[6] = (short)f2bf(v1.z); p[7] = (short)f2bf(v1.w);
  return p;
}

__device__ inline void mfma_step(const unsigned short* As, const unsigned short* Bs,
                                 f32x4 acc[4][4], int wm, int wn, int lane) {
  int r15 = lane & 15, koct = (lane >> 4) * 8;
  short8 a[4], b[4];
#pragma unroll
  for (int mf = 0; mf < 4; mf++)
    a[mf] = *(const short8*)(As + (wm * 64 + mf * 16 + r15) * APAD + koct);
#pragma unroll
  for (int nf = 0; nf < 4; nf++)
    b[nf] = *(const short8*)(Bs + (wn * 64 + nf * 16 + r15) * APAD + koct);
#pragma unroll
  for (int mf = 0; mf < 4; mf++)
#pragma unroll
    for (int nf = 0; nf < 4; nf++)
      acc[mf][nf] = __builtin_amdgcn_mfma_f32_16x16x32_bf16(a[mf], b[nf], acc[mf][nf], 0, 0, 0);
}

// Pipelined K-loop: double-buffered LDS, ONE sync/iter, register prefetch.
template <int NT, class FA, class FB>
__device__ inline void gemm_pipe(FA loadA, FB loadB, SmemGemm& sm,
                                 f32x4 acc[4][4], int wm, int wn, int lane, int tid) {
  int r = tid >> 2, ko = (tid & 3) * 8;
  short8 a0, a1, b0, b1;
  loadA(0, a0, a1); loadB(0, b0, b1);
#pragma unroll
  for (int t = 0; t < NT; t++) {
    unsigned short* As = (t & 1) ? sm.As1 : sm.As0;
    unsigned short* Bs = (t & 1) ? sm.Bs1 : sm.Bs0;
    *(short8*)(As + r * APAD + ko) = a0;
    *(short8*)(As + (r + 64) * APAD + ko) = a1;
    *(short8*)(Bs + r * APAD + ko) = b0;
    *(short8*)(Bs + (r + 64) * APAD + ko) = b1;
    short8 na0, na1, nb0, nb1;
    if (t + 1 < NT) { loadA(t + 1, na0, na1); loadB(t + 1, nb0, nb1); }
    __syncthreads();
    mfma_step(As, Bs, acc, wm, wn, lane);
    if (t + 1 < NT) { a0 = na0; a1 = na1; b0 = nb0; b1 = nb1; }
  }
}

// Single-buffered loop (one-time kernels)
template <int NT, class FA, class FB>
__device__ inline void gemm_simple(FA loadA, FB loadB, SmemGemmS& sm,
                                   f32x4 acc[4][4], int wm, int wn, int lane, int tid) {
  int r = tid >> 2, ko = (tid & 3) * 8;
#pragma unroll 2
  for (int t = 0; t < NT; t++) {
    short8 a0, a1, b0, b1;
    loadA(t, a0, a1); loadB(t, b0, b1);
    *(short8*)(sm.As + r * APAD + ko) = a0;
    *(short8*)(sm.As + (r + 64) * APAD + ko) = a1;
    *(short8*)(sm.Bs + r * APAD + ko) = b0;
    *(short8*)(sm.Bs + (r + 64) * APAD + ko) = b1;
    __syncthreads();
    mfma_step(sm.As, sm.Bs, acc, wm, wn, lane);
    __syncthreads();
  }
}

// D layout (HW-verified m89): col = lane&15, row = (lane>>4)*4 + j
__device__ inline void mfma_epilogue(float* __restrict__ out, int ldo, int m0, int n0,
                                     int Nmax, const float* __restrict__ bias,
                                     const unsigned char* __restrict__ mask,
                                     const float* __restrict__ base,
                                     f32x4 acc[4][4], int wm, int wn, int lane) {
  int rb = (lane >> 4) * 4, cb = lane & 15;
#pragma unroll
  for (int nf = 0; nf < 4; nf++) {
    int col = n0 + wn * 64 + nf * 16 + cb;
    if (col >= Nmax) continue;
    float bv = bias ? bias[col] : 0.f;
#pragma unroll
    for (int mf = 0; mf < 4; mf++) {
#pragma unroll
      for (int j = 0; j < 4; j++) {
        int row = m0 + wm * 64 + mf * 16 + rb + j;
        float v = acc[mf][nf][j] + bv;
        if (base) v += base[(size_t)row * ldo + col];
        if (mask && mask[row]) v = 0.f;
        out[(size_t)row * ldo + col] = v;
      }
    }
  }
}

__device__ inline void mfma_epilogue_bf16(unsigned short* __restrict__ out, int ldo, int n0,
                                          f32x4 acc[4][4], int wm, int wn, int lane) {
  int rb = (lane >> 4) * 4, cb = lane & 15;
#pragma unroll
  for (int nf = 0; nf < 4; nf++) {
    int col = n0 + wn * 64 + nf * 16 + cb;
#pragma unroll
    for (int mf = 0; mf < 4; mf++) {
#pragma unroll
      for (int j = 0; j < 4; j++) {
        int row = wm * 64 + mf * 16 + rb + j;
        out[(size_t)row * ldo + col] = f2bf(acc[mf][nf][j]);
      }
    }
  }
}

#define ACC_INIT f32x4 acc[4][4]; { f32x4 z = {0.f,0.f,0.f,0.f}; \
  _Pragma("unroll") for (int i_=0;i_<4;i_++) _Pragma("unroll") for (int j_=0;j_<4;j_++) acc[i_][j_]=z; }

// ================= kernels =================

// one-time: weight converts (Wih/Whh row-PERMUTED) + inits + ctxW transpose + embed gather
__global__ __launch_bounds__(256) void k_prep(const float* __restrict__ logitW,
    const float* __restrict__ Wih, const float* __restrict__ Whh,
    const float* __restrict__ offW, const float* __restrict__ awW,
    const float* __restrict__ hsW, const float* __restrict__ valueW,
    const float* __restrict__ query, const float* __restrict__ ctxW,
    const int* __restrict__ seq, const float* __restrict__ embedW,
    unsigned short* __restrict__ logitWbf, unsigned short* __restrict__ Wihbf,
    unsigned short* __restrict__ Whhbf, unsigned short* __restrict__ offWbf,
    unsigned short* __restrict__ awWbf, unsigned short* __restrict__ hsWbf,
    unsigned short* __restrict__ valueWbf, unsigned short* __restrict__ qbf,
    float* __restrict__ ctxWT, unsigned short* __restrict__ hall, float* __restrict__ c0,
    unsigned short* __restrict__ xembbf) {
  int gi = blockIdx.x * 256 + threadIdx.x;
  const int e0 = 1536000, e1 = e0 + 786432, e2 = e1 + 262144, e3 = e2 + 32768,
            e4 = e3 + 32768, e5 = e4 + 65536, e6 = e5 + 65536, e7 = e6 + 16384;
  const int e8 = e7 + 16384, e9 = e8 + 8192, e10 = e9 + 245760;
  if (gi < e7) {
    const float* src; unsigned short* dst; int lo, dsti;
    if (gi < e0)      { src = logitW; dst = logitWbf; lo = gi; dsti = lo; }
    else if (gi < e1) {
      src = Wih; dst = Wihbf; lo = gi - e0;
      int row = lo / 384, c4 = lo - row * 384;
      int g = row >> 9, d = row & 511, n = d >> 5, rr = d & 31;
      dsti = (n * 128 + g * 32 + rr) * 384 + c4;
    }
    else if (gi < e2) {
      src = Whh; dst = Whhbf; lo = gi - e1;
      int row = lo >> 7, c4 = lo & 127;
      int g = row >> 9, d = row & 511, n = d >> 5, rr = d & 31;
      dsti = (n * 128 + g * 32 + rr) * 128 + c4;
    }
    else if (gi < e3) { src = offW;   dst = offWbf;   lo = gi - e2; dsti = lo; }
    else if (gi < e4) { src = awW;    dst = awWbf;    lo = gi - e3; dsti = lo; }
    else if (gi < e5) { src = hsW;    dst = hsWbf;    lo = gi - e4; dsti = lo; }
    else if (gi < e6) { src = valueW; dst = valueWbf; lo = gi - e5; dsti = lo; }
    else              { src = query;  dst = qbf;      lo = gi - e6; dsti = lo; }
    float4 v = ((const float4*)src)[lo];
    ushort4 o;
    o.x = f2bf(v.x); o.y = f2bf(v.y); o.z = f2bf(v.z); o.w = f2bf(v.w);
    ((ushort4*)dst)[dsti] = o;
  } else if (gi < e8) {
    int i = gi - e7;
    ushort4 z4; z4.x = 0; z4.y = 0; z4.z = 0; z4.w = 0;
    ((ushort4*)hall)[i] = z4;            // hall slot 0 = h_0 = 0
    float4 z = {0.f, 0.f, 0.f, 0.f};
    ((float4*)c0)[i] = z;
  } else if (gi < e9) {
    int i = gi - e8;
    int k = i >> 7, d4 = i & 127;
    float4 o;
    o.x = ctxW[(d4 * 4 + 0) * 64 + k];
    o.y = ctxW[(d4 * 4 + 1) * 64 + k];
    o.z = ctxW[(d4 * 4 + 2) * 64 + k];
    o.w = ctxW[(d4 * 4 + 3) * 64 + k];
    ((float4*)ctxWT)[k * 128 + d4] = o;
  } else if (gi < e10) {
    int i = gi - e9;
    int row = i >> 7, d4 = i & 127;
    int t = row >> 7, bq = row & 127;
    int tok = seq[bq * T_ + t];
    float4 v = ((const float4*)embedW)[(size_t)tok * 128 + d4];
    ushort4 o;
    o.x = f2bf(v.x); o.y = f2bf(v.y); o.z = f2bf(v.z); o.w = f2bf(v.w);
    ((ushort4*)xembbf)[(size_t)row * 128 + d4] = o;
  }
}

// one-time: value = enc @ valueW^T + b (masked), 480 blocks XCD-swizzled
__global__ __launch_bounds__(256) void k_value(const float* __restrict__ enc,
    const unsigned short* __restrict__ valueWbf, const float* __restrict__ valueb,
    const unsigned char* __restrict__ mask, float* __restrict__ value) {
  __shared__ SmemGemmS sm;
  int blk = blockIdx.x;
  int xcd = blk & 7, j = blk >> 3;
  int m0 = (xcd * 15 + (j >> 2)) * 128, n0 = (j & 3) * 128;
  int tid = threadIdx.x;
  int lane = tid & 63, w = tid >> 6, wm = w >> 1, wn = w & 1;
  int r = tid >> 2, ko = (tid & 3) * 8;
  ACC_INIT;
  gemm_simple<16>(
    [&](int t, short8& x, short8& y) {
      const float4* s0 = (const float4*)(enc + (size_t)(m0 + r) * 512 + t * 32 + ko);
      const float4* s1 = (const float4*)(enc + (size_t)(m0 + r + 64) * 512 + t * 32 + ko);
      x = cvt8(s0[0], s0[1]); y = cvt8(s1[0], s1[1]);
    },
    [&](int t, short8& x, short8& y) {
      x = *(const short8*)(valueWbf + (size_t)(n0 + r) * 512 + t * 32 + ko);
      y = *(const short8*)(valueWbf + (size_t)(n0 + r + 64) * 512 + t * 32 + ko);
    },
    sm, acc, wm, wn, lane, tid);
  mfma_epilogue(value, 512, m0, n0, 512, valueb, mask, nullptr, acc, wm, wn, lane);
}

// one-time: qproj (2 blocks) + gates_pre (240 blocks, XCD-swizzled, permuted Wih)
__global__ __launch_bounds__(256) void k_qg(const unsigned short* __restrict__ qbf,
    const unsigned short* __restrict__ offWbf, const float* __restrict__ offb,
    const unsigned short* __restrict__ awWbf, const float* __restrict__ awb,
    float* __restrict__ off_base, float* __restrict__ aw_base,
    const unsigned short* __restrict__ xembbf,
    const unsigned short* __restrict__ Wihbf, unsigned short* __restrict__ gates_base) {
  __shared__ SmemGemmS sm;
  int blk = blockIdx.x;
  int tid = threadIdx.x;
  int lane = tid & 63, w = tid >> 6, wm = w >> 1, wn = w & 1;
  int r = tid >> 2, ko = (tid & 3) * 8;
  if (blk < 2) {
    const unsigned short* Bw = blk ? awWbf : offWbf;
    const float* bias = blk ? awb : offb;
    float* out = blk ? aw_base : off_base;
    ACC_INIT;
    gemm_simple<16>(
      [&](int t, short8& x, short8& y) {
        x = *(const short8*)(qbf + (size_t)r * 512 + t * 32 + ko);
        y = *(const short8*)(qbf + (size_t)(r + 64) * 512 + t * 32 + ko);
      },
      [&](int t, short8& x, short8& y) {
        x = *(const short8*)(Bw + (size_t)r * 1024 + 512 + t * 32 + ko);
        y = *(const short8*)(Bw + (size_t)(r + 64) * 1024 + 512 + t * 32 + ko);
      },
      sm, acc, wm, wn, lane, tid);
    mfma_epilogue(out, 128, 0, 0, 128, bias, nullptr, nullptr, acc, wm, wn, lane);
  } else {
    int g = blk - 2;
    int xcd = g & 7, j = g >> 3;
    int n0 = (xcd * 2 + (j >= 15)) * 128;
    int st = (j >= 15) ? (j - 15) : j;
    const unsigned short* xa = xembbf + (size_t)(st * 128) * 512;
    ACC_INIT;
    gemm_simple<32>(
      [&](int t, short8& x, short8& y) {
        const unsigned short* src = (t < 16) ? xa : qbf;
        int kk = (t < 16) ? t * 32 : (t - 16) * 32;
        x = *(const short8*)(src + (size_t)r * 512 + kk + ko);
        y = *(const short8*)(src + (size_t)(r + 64) * 512 + kk + ko);
      },
      [&](int t, short8& x, short8& y) {
        int kk = (t < 16) ? t * 32 : 1024 + (t - 16) * 32;
        x = *(const short8*)(Wihbf + (size_t)(n0 + r) * 1536 + kk + ko);
        y = *(const short8*)(Wihbf + (size_t)(n0 + r + 64) * 1536 + kk + ko);
      },
      sm, acc, wm, wn, lane, tid);
    mfma_epilogue_bf16(gates_base + (size_t)st * 128 * 2048, 2048, n0, acc, wm, wn, lane);
  }
}

// per-step: deformable sampling + tanh additive attention (1024 blocks)
__global__ __launch_bounds__(256) void k_sample(const float* __restrict__ value,
    const float* __restrict__ off_src, const float* __restrict__ aw_src,
    const float* __restrict__ hp_src, int hstride,
    const float* __restrict__ refp, const float* __restrict__ vrat,
    const float* __restrict__ ctxWT, const float* __restrict__ ctxb,
    const float* __restrict__ alphaW, const float* __restrict__ alphab,
    unsigned short* __restrict__ attnbf) {
  __shared__ SmemSample sm;
  int blk = blockIdx.x;
  int bq = blk >> 3, h = blk & 7;
  int b = bq >> 5;
  int tid = threadIdx.x;
  int lane = tid & 63, wid = tid >> 6;

  if (tid < 16) {
    float v = aw_src[bq * 128 + h * 16 + tid];
    float m = v;
#pragma unroll
    for (int o = 8; o; o >>= 1) m = fmaxf(m, __shfl_xor(m, o, 16));
    float e = __expf(v - m);
    float s = e;
#pragma unroll
    for (int o = 8; o; o >>= 1) s += __shfl_xor(s, o, 16);
    sm.aw_s[tid] = e / s;
  }
  __syncthreads();

  {
    const int TSv[4] = {2048, 1024, 512, 256};
    const int LSv[4] = {0, 2048, 3072, 3584};
    float ref = refp[bq];
    int hd = tid & 63;
#pragma unroll
    for (int pp = 0; pp < 4; pp++) {
      int p = pp * 4 + (tid >> 6);
      int l = p >> 2;
      int Tl = TSv[l];
      float off = off_src[bq * 128 + h * 16 + p];
      float loc = ref * vrat[b * L_ + l] + off / (float)Tl;
      float x = loc * (float)Tl - 0.5f;
      float x0 = floorf(x);
      float wf = x - x0;
      int i0 = (int)x0;
      const float* vb = value + ((size_t)(b * S_ + LSv[l]) * D_) + h * HD_ + hd;
      float v0 = (i0 >= 0 && i0 < Tl) ? vb[(size_t)i0 * D_] : 0.f;
      float v1 = (i0 + 1 >= 0 && i0 + 1 < Tl) ? vb[(size_t)(i0 + 1) * D_] : 0.f;
      sm.ctx_s[p][hd] = (v0 * (1.f - wf) + v1 * wf) * sm.aw_s[p];
    }
  }
  __syncthreads();

  float2 sacc[16];
#pragma unroll
  for (int p = 0; p < 16; p++) { sacc[p].x = 0.f; sacc[p].y = 0.f; }
  for (int k4 = 0; k4 < 16; k4++) {
    float2 wv[4];
#pragma unroll
    for (int kk = 0; kk < 4; kk++)
      wv[kk] = *(const float2*)(ctxWT + (k4 * 4 + kk) * 512 + 2 * tid);
#pragma unroll
    for (int p = 0; p < 16; p++) {
      float4 c = *(const float4*)(&sm.ctx_s[p][k4 * 4]);
      sacc[p].x += c.x * wv[0].x + c.y * wv[1].x + c.z * wv[2].x + c.w * wv[3].x;
      sacc[p].y += c.x * wv[0].y + c.y * wv[1].y + c.z * wv[2].y + c.w * wv[3].y;
    }
  }

  {
    float2 cb = *(const float2*)(ctxb + 2 * tid);
    float2 hp = *(const float2*)(hp_src + (size_t)hstride * bq + 2 * tid);
    float2 al = *(const float2*)(alphaW + 2 * tid);
    float part[16];
#pragma unroll
    for (int p = 0; p < 16; p++)
      part[p] = al.x * fast_tanh(sacc[p].x + cb.x + hp.x) +
                al.y * fast_tanh(sacc[p].y + cb.y + hp.y);
#pragma unroll
    for (int o = 32; o; o >>= 1)
#pragma unroll
      for (int p = 0; p < 16; p++) part[p] += __shfl_xor(part[p], o, 64);
    if (lane == 0)
#pragma unroll
      for (int p = 0; p < 16; p++) sm.wred[wid][p] = part[p];
  }
  __syncthreads();
  if (tid < 16) {
    float v = sm.wred[0][tid] + sm.wred[1][tid] + sm.wred[2][tid] + sm.wred[3][tid] + alphab[0];
    float m = v;
#pragma unroll
    for (int o = 8; o; o >>= 1) m = fmaxf(m, __shfl_xor(m, o, 16));
    float e = __expf(v - m);
    float s = e;
#pragma unroll
    for (int o = 8; o; o >>= 1) s += __shfl_xor(s, o, 16);
    sm.wgt_s[tid] = e / s;
  }
  __syncthreads();
  if (tid < 64) {
    float a = 0.f;
#pragma unroll
    for (int pi = 0; pi < 16; pi++) a += sm.wgt_s[pi] * sm.ctx_s[pi][tid];
    attnbf[bq * D_ + h * HD_ + tid] = f2bf(a);
  }
}

// per-step LSTM gates, split-K: K=1024 over [attn|h], 4 chunks (permuted weights)
__global__ __launch_bounds__(256) void k_lstm_gemm(
    const unsigned short* __restrict__ attnbf, const unsigned short* __restrict__ hcur,
    const unsigned short* __restrict__ Wihbf, const unsigned short* __restrict__ Whhbf,
    float* __restrict__ gpart) {
  __shared__ SmemGemm sm;
  int tid = threadIdx.x;
  int lane = tid & 63, w = tid >> 6, wm = w >> 1, wn = w & 1;
  int r = tid >> 2, ko = (tid & 3) * 8;
  int n0 = blockIdx.x * 128;
  int kc = blockIdx.y;
  const unsigned short* Asrc = (kc < 2) ? (attnbf + kc * 256) : (hcur + (kc - 2) * 256);
  const unsigned short* Bsrc = (kc < 2) ? (Wihbf + (size_t)n0 * 1536 + 512 + kc * 256)
                                        : (Whhbf + (size_t)n0 * 512 + (kc - 2) * 256);
  int ldB = (kc < 2) ? 1536 : 512;
  ACC_INIT;
  gemm_pipe<8>(
    [&](int t, short8& x, short8& y) {
      x = *(const short8*)(Asrc + (size_t)r * 512 + t * 32 + ko);
      y = *(const short8*)(Asrc + (size_t)(r + 64) * 512 + t * 32 + ko);
    },
    [&](int t, short8& x, short8& y) {
      x = *(const short8*)(Bsrc + (size_t)r * ldB + t * 32 + ko);
      y = *(const short8*)(Bsrc + (size_t)(r + 64) * ldB + t * 32 + ko);
    },
    sm, acc, wm, wn, lane, tid);
  mfma_epilogue(gpart + (size_t)kc * 262144, 2048, 0, n0, 2048,
                nullptr, nullptr, nullptr, acc, wm, wn, lane);
}

// LSTM cell: fused split-K reduce + base add + nonlinearity (permuted gate columns)
__global__ __launch_bounds__(256) void k_cell(const float* __restrict__ gpart,
    const unsigned short* __restrict__ gbase_t,
    const float* __restrict__ c, float* __restrict__ cn, unsigned short* __restrict__ hout) {
  int idx = blockIdx.x * 256 + threadIdx.x;
  int bq = idx >> 9, d = idx & 511;
  int n = d >> 5, rr = d & 31;
  size_t rowoff = (size_t)bq * 2048 + n * 128 + rr;
  float g4[4];
#pragma unroll
  for (int gate = 0; gate < 4; gate++) {
    size_t off = rowoff + gate * 32;
    float s = bf2f(gbase_t[off]);
    s += gpart[off] + gpart[262144 + off] + gpart[2 * 262144 + off] + gpart[3 * 262144 + off];
    g4[gate] = s;
  }
  float cc = c[idx];
  float c2 = sigmoidf_(g4[1]) * cc + sigmoidf_(g4[0]) * fast_tanh(g4[2]);
  float h2 = sigmoidf_(g4[3]) * fast_tanh(c2);
  cn[idx] = c2;
  hout[idx] = f2bf(h2);
}

// per-step projections: off/aw (h half) + hproj; 6 blocks
__global__ __launch_bounds__(256) void k_pre(const unsigned short* __restrict__ hbf,
    const unsigned short* __restrict__ offWbf, const unsigned short* __restrict__ awWbf,
    const unsigned short* __restrict__ hsWbf, const float* __restrict__ hsb,
    const float* __restrict__ off_base, const float* __restrict__ aw_base,
    float* __restrict__ offo, float* __restrict__ awo, float* __restrict__ hpo) {
  __shared__ SmemGemm sm;
  int blk = blockIdx.x;
  const unsigned short* Bw; const float* bias; const float* base;
  float* out; int ldkB, n0, ldo;
  if (blk == 0)      { Bw = offWbf; bias = nullptr; base = off_base; out = offo; ldkB = 1024; n0 = 0; ldo = 128; }
  else if (blk == 1) { Bw = awWbf;  bias = nullptr; base = aw_base;  out = awo;  ldkB = 1024; n0 = 0; ldo = 128; }
  else { Bw = hsWbf; bias = hsb; base = nullptr; out = hpo; ldkB = 512; n0 = (blk - 2) * 128; ldo = 512; }
  int tid = threadIdx.x;
  int lane = tid & 63, w = tid >> 6, wm = w >> 1, wn = w & 1;
  int r = tid >> 2, ko = (tid & 3) * 8;
  ACC_INIT;
  gemm_pipe<16>(
    [&](int t, short8& x, short8& y) {
      x = *(const short8*)(hbf + (size_t)r * 512 + t * 32 + ko);
      y = *(const short8*)(hbf + (size_t)(r + 64) * 512 + t * 32 + ko);
    },
    [&](int t, short8& x, short8& y) {
      x = *(const short8*)(Bw + (size_t)(n0 + r) * ldkB + t * 32 + ko);
      y = *(const short8*)(Bw + (size_t)(n0 + r + 64) * ldkB + t * 32 + ko);
    },
    sm, acc, wm, wn, lane, tid);
  mfma_epilogue(out, ldo, 0, n0, ldo, bias, nullptr, base, acc, wm, wn, lane);
}

// batched logits for ALL steps as ONE plain GEMM: M=15x128, N=12000, K=512.
// Grid: 1416 blocks (6 pad), bijective XCD-chunk swizzle so same-slab blocks
// share an XCD L2. High occupancy (43KB LDS -> 3 blocks/CU), no pinning.
__global__ __launch_bounds__(256) void k_logits_big(
    const unsigned short* __restrict__ logitWbf, const float* __restrict__ logitb,
    const unsigned short* __restrict__ hall, float* __restrict__ outp,
    float* __restrict__ m_sb, float* __restrict__ s_sb) {
  __shared__ SmemGemm sm;
  __shared__ float mred[128][2], sred[128][2];
  int blk = blockIdx.x;
  int swz = (blk & 7) * 177 + (blk >> 3);     // XCD-chunked over 1416=8*177
  if (swz >= NSLAB * NSTEP) return;
  int slab = swz / NSTEP, t = swz % NSTEP;
  int n0 = slab * 128;
  int tid = threadIdx.x;
  int lane = tid & 63, w = tid >> 6, wm = w >> 1, wn = w & 1;
  int r = tid >> 2, ko = (tid & 3) * 8;
  const unsigned short* hn = hall + (size_t)(t + 1) * 65536;
  bool ok0 = (n0 + r) < V_, ok1 = (n0 + r + 64) < V_;
  ACC_INIT;
  gemm_pipe<16>(
    [&](int tt, short8& x, short8& y) {
      x = *(const short8*)(hn + (size_t)r * 512 + tt * 32 + ko);
      y = *(const short8*)(hn + (size_t)(r + 64) * 512 + tt * 32 + ko);
    },
    [&](int tt, short8& x, short8& y) {
      short8 z = {0, 0, 0, 0, 0, 0, 0, 0};
      x = ok0 ? *(const short8*)(logitWbf + (size_t)(n0 + r) * 512 + tt * 32 + ko) : z;
      y = ok1 ? *(const short8*)(logitWbf + (size_t)(n0 + r + 64) * 512 + tt * 32 + ko) : z;
    },
    sm, acc, wm, wn, lane, tid);
  // epilogue: raw logits+bias -> d_out slice; per-row slab (max, expsum) partials
  int rb = (lane >> 4) * 4, cb = lane & 15;
#pragma unroll
  for (int mf = 0; mf < 4; mf++) {
#pragma unroll
    for (int j = 0; j < 4; j++) {
      int row = wm * 64 + mf * 16 + rb + j;
      float vv[4];
      float mx = -3.4e38f;
#pragma unroll
      for (int nf = 0; nf < 4; nf++) {
        int col = n0 + wn * 64 + nf * 16 + cb;
        bool ok = col < V_;
        float v = ok ? (acc[mf][nf][j] + logitb[col]) : -3.4e38f;
        if (ok) outp[((size_t)row * NSTEP + t) * V_ + col] = v;
        vv[nf] = v;
        mx = fmaxf(mx, v);
      }
#pragma unroll
      for (int o = 8; o; o >>= 1) mx = fmaxf(mx, __shfl_xor(mx, o, 16));
      float sme = 0.f;
#pragma unroll
      for (int nf = 0; nf < 4; nf++) sme += (vv[nf] > -3.0e38f) ? __expf(vv[nf] - mx) : 0.f;
#pragma unroll
      for (int o = 8; o; o >>= 1) sme += __shfl_xor(sme, o, 16);
      if (cb == 0) { mred[row][wn] = mx; sred[row][wn] = sme; }
    }
  }
  __syncthreads();
  if (tid < 128) {
    float m0 = mred[tid][0], m1 = mred[tid][1];
    float M = fmaxf(m0, m1);
    float Ssum = sred[tid][0] * __expf(m0 - M) + sred[tid][1] * __expf(m1 - M);
    m_sb[((size_t)t * 128 + tid) * 96 + slab] = M;
    s_sb[((size_t)t * 128 + tid) * 96 + slab] = Ssum;
  }
}

// final: per (t,row) combine partials -> lse, subtract in-place in d_out
__global__ __launch_bounds__(256) void k_out_all(const float* __restrict__ m_sb,
    const float* __restrict__ s_sb, float* __restrict__ outp) {
  __shared__ float ms[NSLAB], ss[NSLAB];
  __shared__ float lse_s;
  int blk = blockIdx.x;                 // 1920 = 15*128
  int t = blk >> 7, row = blk & 127;
  int tid = threadIdx.x;
  size_t pbase = ((size_t)t * 128 + row) * 96;
  if (tid < NSLAB) { ms[tid] = m_sb[pbase + tid]; ss[tid] = s_sb[pbase + tid]; }
  __syncthreads();
  if (tid < 64) {
    float m = -3.4e38f, s = 0.f;
    for (int i = tid; i < NSLAB; i += 64) {
      float mi = ms[i], si = ss[i];
      float M = fmaxf(m, mi);
      s = s * __expf(m - M) + si * __expf(mi - M);
      m = M;
    }
#pragma unroll
    for (int o = 32; o; o >>= 1) {
      float mo = __shfl_xor(m, o, 64), so = __shfl_xor(s, o, 64);
      float M = fmaxf(m, mo);
      s = s * __expf(m - M) + so * __expf(mo - M);
      m = M;
    }
    if (tid == 0) lse_s = m + __logf(s);
  }
  __syncthreads();
  float lse = lse_s;
  float4* op = (float4*)(outp + ((size_t)row * NSTEP + t) * V_);
  for (int i = tid; i < V_ / 4; i += 256) {
    float4 v = op[i];
    v.x -= lse; v.y -= lse; v.z -= lse; v.w -= lse;
    op[i] = v;
  }
}

// ---------------- host launch ----------------
extern "C" void kernel_launch(void* const* d_in, const int* in_sizes, int n_in,
                              void* d_out, int out_size, void* d_ws, size_t ws_size,
                              hipStream_t stream) {
  const int* seq             = (const int*)d_in[0];
  const float* query         = (const float*)d_in[1];
  const float* refp          = (const float*)d_in[2];
  const float* enc           = (const float*)d_in[3];
  const float* vrat          = (const float*)d_in[4];
  const unsigned char* mask  = (const unsigned char*)d_in[5];
  const float* embedW        = (const float*)d_in[8];
  const float* logitW        = (const float*)d_in[9];
  const float* logitb        = (const float*)d_in[10];
  const float* Wih           = (const float*)d_in[11];
  const float* Whh           = (const float*)d_in[12];
  const float* valueW        = (const float*)d_in[13];
  const float* valueb        = (const float*)d_in[14];
  const float* offW          = (const float*)d_in[15];
  const float* offb          = (const float*)d_in[16];
  const float* awW           = (const float*)d_in[17];
  const float* awb           = (const float*)d_in[18];
  const float* ctxW          = (const float*)d_in[19];
  const float* ctxb          = (const float*)d_in[20];
  const float* hsW           = (const float*)d_in[21];
  const float* hsb           = (const float*)d_in[22];
  const float* alphaW        = (const float*)d_in[23];
  const float* alphab        = (const float*)d_in[24];

  char* wp = (char*)d_ws;
  auto alloc_f = [&](size_t n) { float* p = (float*)wp; wp += ((n * 4 + 255) / 256) * 256; return p; };
  auto alloc_u = [&](size_t n) { unsigned short* p = (unsigned short*)wp; wp += ((n * 2 + 255) / 256) * 256; return p; };

  float* value   = alloc_f((size_t)B_ * S_ * D_);
  float* gpart   = alloc_f((size_t)4 * BQ_ * 2048);
  float* hproj   = alloc_f((size_t)BQ_ * D_);
  float* offo    = alloc_f((size_t)BQ_ * 128);
  float* awo     = alloc_f((size_t)BQ_ * 128);
  float* off_base= alloc_f((size_t)BQ_ * 128);
  float* aw_base = alloc_f((size_t)BQ_ * 128);
  float* c0      = alloc_f((size_t)BQ_ * D_);
  float* c1      = alloc_f((size_t)BQ_ * D_);
  float* ctxWT   = alloc_f((size_t)64 * 512);
  float* m_sb    = alloc_f((size_t)NSTEP * BQ_ * 96);
  float* s_sb    = alloc_f((size_t)NSTEP * BQ_ * 96);
  unsigned short* hall    = alloc_u((size_t)(NSTEP + 1) * BQ_ * D_);  // h_0..h_15
  unsigned short* attnbf  = alloc_u((size_t)BQ_ * D_);
  unsigned short* qbf     = alloc_u((size_t)BQ_ * D_);
  unsigned short* xembbf  = alloc_u((size_t)NSTEP * BQ_ * D_);
  unsigned short* gates_base = alloc_u((size_t)NSTEP * BQ_ * 2048);
  unsigned short* logitWbf = alloc_u((size_t)V_ * D_);
  unsigned short* Wihbf    = alloc_u((size_t)2048 * 1536);
  unsigned short* Whhbf    = alloc_u((size_t)2048 * 512);
  unsigned short* offWbf   = alloc_u((size_t)128 * 1024);
  unsigned short* awWbf    = alloc_u((size_t)128 * 1024);
  unsigned short* hsWbf    = alloc_u((size_t)512 * 512);
  unsigned short* valueWbf = alloc_u((size_t)512 * 512);

  // one-time
  k_prep<<<11984, 256, 0, stream>>>(logitW, Wih, Whh, offW, awW, hsW, valueW, query, ctxW,
                                    seq, embedW,
                                    logitWbf, Wihbf, Whhbf, offWbf, awWbf, hsWbf,
                                    valueWbf, qbf, ctxWT, hall, c0, xembbf);
  k_value<<<480, 256, 0, stream>>>(enc, valueWbf, valueb, mask, value);
  k_qg<<<242, 256, 0, stream>>>(qbf, offWbf, offb, awWbf, awb, off_base, aw_base,
                                xembbf, Wihbf, gates_base);

  float* cb[2] = {c0, c1};
  float* outp = (float*)d_out;

  // recurrence loop: only small kernels on the critical chain
  for (int t = 0; t < NSTEP; t++) {
    const unsigned short* hcur = hall + (size_t)t * BQ_ * D_;
    unsigned short* hnxt = hall + (size_t)(t + 1) * BQ_ * D_;
    if (t == 0)
      k_sample<<<1024, 256, 0, stream>>>(value, off_base, aw_base, hsb, 0, refp, vrat,
                                         ctxWT, ctxb, alphaW, alphab, attnbf);
    else
      k_sample<<<1024, 256, 0, stream>>>(value, offo, awo, hproj, 512, refp, vrat,
                                         ctxWT, ctxb, alphaW, alphab, attnbf);
    k_lstm_gemm<<<dim3(16, 4), 256, 0, stream>>>(attnbf, hcur, Wihbf, Whhbf, gpart);
    k_cell<<<256, 256, 0, stream>>>(gpart, gates_base + (size_t)t * BQ_ * 2048,
                                    cb[t & 1], cb[(t + 1) & 1], hnxt);
    if (t + 1 < NSTEP)
      k_pre<<<6, 256, 0, stream>>>(hnxt, offWbf, awWbf, hsWbf, hsb,
                                   off_base, aw_base, offo, awo, hproj);
  }

  // batched logits as one big GEMM + final lse subtract
  k_logits_big<<<1416, 256, 0, stream>>>(logitWbf, logitb, hall, outp, m_sb, s_sb);
  k_out_all<<<NSTEP * BQ_, 256, 0, stream>>>(m_sb, s_sb, outp);
}